// Round 2
// baseline (236.862 us; speedup 1.0000x reference)
//
#include <hip/hip_runtime.h>
#include <stdint.h>
#include <math.h>

typedef unsigned short u16;
typedef unsigned int u32;
typedef __attribute__((ext_vector_type(8))) short bf16x8;   // 8 bf16 (4 VGPRs) MFMA A/B frag
typedef __attribute__((ext_vector_type(4))) float f32x4;
typedef __attribute__((ext_vector_type(2))) float f32x2;
typedef __attribute__((ext_vector_type(2))) u16 u16x2;
typedef __attribute__((ext_vector_type(8))) u16 u16x8;

#define B_ 8
#define T_ 1024
#define D_ 512
#define H_ 8
#define TP1 1025

__device__ __forceinline__ u16 f2b(float f) {           // f32 -> bf16 RNE
  union { float f; u32 u; } v; v.f = f;
  return (u16)((v.u + 0x7fffu + ((v.u >> 16) & 1u)) >> 16);
}
__device__ __forceinline__ float b2f(u16 b) {
  union { u32 u; float f; } v; v.u = ((u32)b) << 16; return v.f;
}
__device__ __forceinline__ void gld16(const void* g, void* l) {
  // async global->LDS, 16B/lane; LDS dest = wave-uniform base + lane*16
  __builtin_amdgcn_global_load_lds((const __attribute__((address_space(1))) u32*)g,
                                   (__attribute__((address_space(3))) u32*)l, 16, 0, 0);
}
__device__ __forceinline__ f32x4 mfma16(bf16x8 a, bf16x8 b, f32x4 c) {
  return __builtin_amdgcn_mfma_f32_16x16x32_bf16(a, b, c, 0, 0, 0);
}

// ---------------- weight transpose + cast: Wt[n][k] = bf16(W[k][n]) ----------------
__global__ __launch_bounds__(256) void transpose_cast(const float* __restrict__ W,
                                                      u16* __restrict__ Wt, int K, int N) {
  int i = blockIdx.x * 256 + threadIdx.x;
  if (i >= K * N) return;
  int n = i / K, k = i % K;
  Wt[i] = f2b(W[(size_t)k * N + n]);
}

// ---------------- RoPE tables: cos/sin for q (pos[t]) and k (pos[t+1]) ----------------
__global__ __launch_bounds__(256) void rope_tables(const float* __restrict__ seq,
    float* __restrict__ cq, float* __restrict__ sq,
    float* __restrict__ ck, float* __restrict__ sk) {
  int i = blockIdx.x * 256 + threadIdx.x;      // B*T*16
  if (i >= B_ * T_ * 16) return;
  int p = i & 15, bt = i >> 4, b = bt >> 10, t = bt & 1023;
  float inv = expf(-(float)p * 0.5756462732485115f);   // 10000^(-p/16)
  float aq = seq[b * TP1 + t] * inv;
  float ak = seq[b * TP1 + t + 1] * inv;
  cq[i] = cosf(aq); sq[i] = sinf(aq);
  ck[i] = cosf(ak); sk[i] = sinf(ak);
}

// ---------------- LayerNorm row kernel: f32 in -> bf16 out ----------------
__global__ __launch_bounds__(256) void ln_kernel(const float* __restrict__ x,
    const float* __restrict__ g, const float* __restrict__ bta, u16* __restrict__ out) {
  int row = blockIdx.x;                       // 8192 rows
  int tid = threadIdx.x;
  const float* xr = x + (size_t)row * D_;
  f32x2 v = *(const f32x2*)(xr + tid * 2);
  float s = v[0] + v[1];
  float sq = v[0] * v[0] + v[1] * v[1];
  #pragma unroll
  for (int m = 32; m; m >>= 1) { s += __shfl_down(s, m); sq += __shfl_down(sq, m); }
  __shared__ float ls[4], lq[4];
  int w = tid >> 6, lane = tid & 63;
  if (lane == 0) { ls[w] = s; lq[w] = sq; }
  __syncthreads();
  if (tid == 0) {
    float a = ls[0] + ls[1] + ls[2] + ls[3];
    float c = lq[0] + lq[1] + lq[2] + lq[3];
    ls[0] = a; lq[0] = c;
  }
  __syncthreads();
  float mean = ls[0] * (1.f / D_);
  float var = lq[0] * (1.f / D_) - mean * mean;
  float rstd = rsqrtf(var + 1e-5f);
  float g0 = g[2 * tid], g1 = g[2 * tid + 1];
  float b0 = bta[2 * tid], b1v = bta[2 * tid + 1];
  u16x2 o;
  o[0] = f2b((v[0] - mean) * rstd * g0 + b0);
  o[1] = f2b((v[1] - mean) * rstd * g1 + b1v);
  *(u16x2*)(out + (size_t)row * D_ + tid * 2) = o;
}

// ============ shared GEMM tile machinery: 128x128 tile, BK=32, 4 waves ============
// staging swizzle: stored[row][p] = global chunk p ^ s(row), s(row)=(row>>1)&3
// read at position g ^ s(row) -> 2-way bank aliasing only (free, m136).

// ---------------- QKV GEMM with fused type-emb + RoPE + scale + head-layout epilogue ----------------
__global__ __launch_bounds__(256) void gemm_qkv(const u16* __restrict__ A,
    const u16* __restrict__ Bt,
    const int* __restrict__ x_type, const float* __restrict__ type_emb,
    const float* __restrict__ rqc, const float* __restrict__ rqs,
    const float* __restrict__ rkc, const float* __restrict__ rks,
    u16* __restrict__ qT, u16* __restrict__ kT, u16* __restrict__ vT) {
  __shared__ u16 lA[128 * 32];
  __shared__ u16 lB[128 * 32];
  const int K = 512;
  const int tid = threadIdx.x, lane = tid & 63, w = tid >> 6;
  const int wm = w >> 1, wn = w & 1;
  const size_t bm = (size_t)blockIdx.y * 128;
  const size_t bn = (size_t)blockIdx.x * 128;

  const int r0 = tid >> 2;
  const int cs = ((tid & 3) ^ ((r0 >> 1) & 3)) * 8;
  const u16* a0 = A + (bm + r0) * K + cs;
  const u16* a1 = A + (bm + 64 + r0) * K + cs;
  const u16* b0 = Bt + (bn + r0) * K + cs;
  const u16* b1p = Bt + (bn + 64 + r0) * K + cs;
  char* lAw0 = (char*)lA + w * 1024;  char* lAw1 = (char*)lA + 4096 + w * 1024;
  char* lBw0 = (char*)lB + w * 1024;  char* lBw1 = (char*)lB + 4096 + w * 1024;

  int aoff[4], boff[4];
  #pragma unroll
  for (int i = 0; i < 4; i++) {
    int ra = wm * 64 + i * 16 + (lane & 15);
    aoff[i] = ra * 64 + (((lane >> 4) ^ ((ra >> 1) & 3)) * 16);
    int rb = wn * 64 + i * 16 + (lane & 15);
    boff[i] = rb * 64 + (((lane >> 4) ^ ((rb >> 1) & 3)) * 16);
  }

  f32x4 acc[4][4] = {};
  for (int k0 = 0; k0 < K; k0 += 32) {
    __syncthreads();
    gld16(a0 + k0, lAw0);
    gld16(a1 + k0, lAw1);
    gld16(b0 + k0, lBw0);
    gld16(b1p + k0, lBw1);
    __syncthreads();
    bf16x8 af[4], bf[4];
    #pragma unroll
    for (int i = 0; i < 4; i++) af[i] = *(const bf16x8*)((const char*)lA + aoff[i]);
    #pragma unroll
    for (int n = 0; n < 4; n++) bf[n] = *(const bf16x8*)((const char*)lB + boff[n]);
    #pragma unroll
    for (int i = 0; i < 4; i++)
      #pragma unroll
      for (int n = 0; n < 4; n++)
        acc[i][n] = mfma16(af[i], bf[n], acc[i][n]);
  }

  // fused epilogue. block-uniform region: 0=q (cols 0..511), 1=k, 2=v
  const int region = (int)(bn >> 9);
  #pragma unroll
  for (int i = 0; i < 4; i++) {
    #pragma unroll
    for (int jj = 0; jj < 4; jj++) {
      int row = (int)bm + wm * 64 + i * 16 + (lane >> 4) * 4 + jj;   // bt index
      int b = row >> 10, t = row & 1023;
      if (region == 0) {
        int ty = x_type[b * TP1 + t];
        #pragma unroll
        for (int n = 0; n < 4; n++) {
          int cloc = (int)bn + wn * 64 + n * 16 + (lane & 15);       // 0..511
          int h = cloc >> 6, hd = cloc & 63;
          float v = acc[i][n][jj] + type_emb[(size_t)ty * 1024 + cloc];
          float vp = __shfl_xor(v, 1);
          if (hd < 32) {
            int p = hd >> 1;
            float c = rqc[row * 16 + p], s = rqs[row * 16 + p];
            v = (hd & 1) ? (v * c + vp * s) : (v * c - vp * s);
          }
          qT[((size_t)(b * 8 + h) * T_ + t) * 64 + hd] = f2b(v * 0.125f);
        }
      } else if (region == 1) {
        int ty = x_type[b * TP1 + t + 1];
        #pragma unroll
        for (int n = 0; n < 4; n++) {
          int cloc = (int)bn - 512 + wn * 64 + n * 16 + (lane & 15); // 0..511
          int h = cloc >> 6, hd = cloc & 63;
          float v = acc[i][n][jj] + type_emb[(size_t)ty * 1024 + 512 + cloc];
          float vp = __shfl_xor(v, 1);
          if (hd < 32) {
            int p = hd >> 1;
            float c = rkc[row * 16 + p], s = rks[row * 16 + p];
            v = (hd & 1) ? (v * c + vp * s) : (v * c - vp * s);
          }
          kT[((size_t)(b * 8 + h) * T_ + t) * 64 + hd] = f2b(v);
        }
      } else {
        #pragma unroll
        for (int n = 0; n < 4; n++) {
          int cloc = (int)bn - 1024 + wn * 64 + n * 16 + (lane & 15);
          int h = cloc >> 6, hd = cloc & 63;
          vT[((size_t)(b * 8 + h) * 64 + hd) * T_ + t] = f2b(acc[i][n][jj]);
        }
      }
    }
  }
}

// ---------------- FF1 GEMM with fused bias + SwiGLU epilogue -> bf16 ----------------
// block computes cols [bn, bn+128) of BOTH the a-half (W1 cols 0..1023) and
// the gate-half (W1 cols 1024..2047); epilogue: silu(g+b)*(a+b) -> ff1a.
__global__ __launch_bounds__(256) void gemm_ff1(const u16* __restrict__ A,
    const u16* __restrict__ Bt, const float* __restrict__ b1,
    u16* __restrict__ outp) {
  __shared__ u16 lA[128 * 32];
  __shared__ u16 lBa[128 * 32];
  __shared__ u16 lBg[128 * 32];
  const int K = 512;
  const int tid = threadIdx.x, lane = tid & 63, w = tid >> 6;
  const int wm = w >> 1, wn = w & 1;
  const size_t bm = (size_t)blockIdx.y * 128;
  const size_t bn = (size_t)blockIdx.x * 128;

  const int r0 = tid >> 2;
  const int cs = ((tid & 3) ^ ((r0 >> 1) & 3)) * 8;
  const u16* a0  = A + (bm + r0) * K + cs;
  const u16* a1  = A + (bm + 64 + r0) * K + cs;
  const u16* ba0 = Bt + (bn + r0) * K + cs;
  const u16* ba1 = Bt + (bn + 64 + r0) * K + cs;
  const u16* bg0 = Bt + (1024 + bn + r0) * K + cs;
  const u16* bg1 = Bt + (1024 + bn + 64 + r0) * K + cs;
  char* lAw0  = (char*)lA  + w * 1024;  char* lAw1  = (char*)lA  + 4096 + w * 1024;
  char* lBaw0 = (char*)lBa + w * 1024;  char* lBaw1 = (char*)lBa + 4096 + w * 1024;
  char* lBgw0 = (char*)lBg + w * 1024;  char* lBgw1 = (char*)lBg + 4096 + w * 1024;

  int aoff[4], boff[4];
  #pragma unroll
  for (int i = 0; i < 4; i++) {
    int ra = wm * 64 + i * 16 + (lane & 15);
    aoff[i] = ra * 64 + (((lane >> 4) ^ ((ra >> 1) & 3)) * 16);
    int rb = wn * 64 + i * 16 + (lane & 15);
    boff[i] = rb * 64 + (((lane >> 4) ^ ((rb >> 1) & 3)) * 16);
  }

  f32x4 aca[4][4] = {}, acg[4][4] = {};
  for (int k0 = 0; k0 < K; k0 += 32) {
    __syncthreads();
    gld16(a0 + k0, lAw0);
    gld16(a1 + k0, lAw1);
    gld16(ba0 + k0, lBaw0);
    gld16(ba1 + k0, lBaw1);
    gld16(bg0 + k0, lBgw0);
    gld16(bg1 + k0, lBgw1);
    __syncthreads();
    bf16x8 af[4], bfa[4], bfg[4];
    #pragma unroll
    for (int i = 0; i < 4; i++) af[i]  = *(const bf16x8*)((const char*)lA  + aoff[i]);
    #pragma unroll
    for (int n = 0; n < 4; n++) bfa[n] = *(const bf16x8*)((const char*)lBa + boff[n]);
    #pragma unroll
    for (int n = 0; n < 4; n++) bfg[n] = *(const bf16x8*)((const char*)lBg + boff[n]);
    #pragma unroll
    for (int i = 0; i < 4; i++) {
      #pragma unroll
      for (int n = 0; n < 4; n++) {
        aca[i][n] = mfma16(af[i], bfa[n], aca[i][n]);
        acg[i][n] = mfma16(af[i], bfg[n], acg[i][n]);
      }
    }
  }
  #pragma unroll
  for (int i = 0; i < 4; i++) {
    #pragma unroll
    for (int n = 0; n < 4; n++) {
      int col = (int)bn + wn * 64 + n * 16 + (lane & 15);
      float bav = b1[col], bgv = b1[1024 + col];
      #pragma unroll
      for (int jj = 0; jj < 4; jj++) {
        int row = (int)bm + wm * 64 + i * 16 + (lane >> 4) * 4 + jj;
        float av = aca[i][n][jj] + bav;
        float gv = acg[i][n][jj] + bgv;
        float sg = gv / (1.f + expf(-gv));
        outp[(size_t)row * 1024 + col] = f2b(sg * av);
      }
    }
  }
}

// ---------------- FF2 GEMM with fused bias + residual (in-place on d_out) ----------------
__global__ __launch_bounds__(256) void gemm_ff2(const u16* __restrict__ A,
    const u16* __restrict__ Bt, const float* __restrict__ bias,
    float* __restrict__ C) {
  __shared__ u16 lA[128 * 32];
  __shared__ u16 lB[128 * 32];
  const int K = 1024, N = 512;
  const int tid = threadIdx.x, lane = tid & 63, w = tid >> 6;
  const int wm = w >> 1, wn = w & 1;
  const size_t bm = (size_t)blockIdx.y * 128;
  const size_t bn = (size_t)blockIdx.x * 128;

  const int r0 = tid >> 2;
  const int cs = ((tid & 3) ^ ((r0 >> 1) & 3)) * 8;
  const u16* a0 = A + (bm + r0) * K + cs;
  const u16* a1 = A + (bm + 64 + r0) * K + cs;
  const u16* b0 = Bt + (bn + r0) * K + cs;
  const u16* b1p = Bt + (bn + 64 + r0) * K + cs;
  char* lAw0 = (char*)lA + w * 1024;  char* lAw1 = (char*)lA + 4096 + w * 1024;
  char* lBw0 = (char*)lB + w * 1024;  char* lBw1 = (char*)lB + 4096 + w * 1024;

  int aoff[4], boff[4];
  #pragma unroll
  for (int i = 0; i < 4; i++) {
    int ra = wm * 64 + i * 16 + (lane & 15);
    aoff[i] = ra * 64 + (((lane >> 4) ^ ((ra >> 1) & 3)) * 16);
    int rb = wn * 64 + i * 16 + (lane & 15);
    boff[i] = rb * 64 + (((lane >> 4) ^ ((rb >> 1) & 3)) * 16);
  }

  f32x4 acc[4][4] = {};
  for (int k0 = 0; k0 < K; k0 += 32) {
    __syncthreads();
    gld16(a0 + k0, lAw0);
    gld16(a1 + k0, lAw1);
    gld16(b0 + k0, lBw0);
    gld16(b1p + k0, lBw1);
    __syncthreads();
    bf16x8 af[4], bf[4];
    #pragma unroll
    for (int i = 0; i < 4; i++) af[i] = *(const bf16x8*)((const char*)lA + aoff[i]);
    #pragma unroll
    for (int n = 0; n < 4; n++) bf[n] = *(const bf16x8*)((const char*)lB + boff[n]);
    #pragma unroll
    for (int i = 0; i < 4; i++)
      #pragma unroll
      for (int n = 0; n < 4; n++)
        acc[i][n] = mfma16(af[i], bf[n], acc[i][n]);
  }
  #pragma unroll
  for (int i = 0; i < 4; i++) {
    size_t mrow = bm + wm * 64 + i * 16 + (lane >> 4) * 4;
    #pragma unroll
    for (int n = 0; n < 4; n++) {
      size_t col = bn + wn * 64 + n * 16 + (lane & 15);
      float bv = bias[col];
      #pragma unroll
      for (int jj = 0; jj < 4; jj++) {
        size_t idx = (mrow + jj) * (size_t)N + col;
        C[idx] = acc[i][n][jj] + bv + C[idx];   // in-place residual
      }
    }
  }
}

// ---------------- causal flash attention + residual: out = x_value + attn ----------------
__global__ __launch_bounds__(256) void attn_kernel(const u16* __restrict__ qT,
    const u16* __restrict__ kT, const u16* __restrict__ vT,
    const float* __restrict__ xv, float* __restrict__ X) {
  const int qb = blockIdx.x;
  const int bh = blockIdx.y;
  const int b = bh >> 3, h = bh & 7;
  const int tid = threadIdx.x, lane = tid & 63, w = tid >> 6;
  __shared__ u16 lK[64 * 64];
  __shared__ u16 lV[64 * 64];
  __shared__ u16 lP[4][16 * 64];

  bf16x8 qf[2];
  {
    int row = qb * 64 + w * 16 + (lane & 15);
    const u16* qp = qT + ((size_t)bh * T_ + row) * 64 + (lane >> 4) * 8;
    qf[0] = *(const bf16x8*)qp;
    qf[1] = *(const bf16x8*)(qp + 32);
  }
  f32x4 acc[4] = {};
  float mr[4], lr[4] = {};
  #pragma unroll
  for (int i = 0; i < 4; i++) mr[i] = -__builtin_inff();

  const int sr = tid >> 3;
  const int scs = ((tid & 7) ^ (sr & 7)) * 8;
  const u16* kbase0 = kT + ((size_t)bh * T_ + sr) * 64 + scs;
  const u16* kbase1 = kT + ((size_t)bh * T_ + 32 + sr) * 64 + scs;
  const u16* vbase0 = vT + ((size_t)bh * 64 + sr) * T_ + scs;
  const u16* vbase1 = vT + ((size_t)bh * 64 + 32 + sr) * T_ + scs;
  char* lKw0 = (char*)lK + w * 1024;  char* lKw1 = (char*)lK + 4096 + w * 1024;
  char* lVw0 = (char*)lV + w * 1024;  char* lVw1 = (char*)lV + 4096 + w * 1024;

  for (int j = 0; j <= qb; j++) {
    gld16(kbase0 + (size_t)j * 64 * 64, lKw0);
    gld16(kbase1 + (size_t)j * 64 * 64, lKw1);
    gld16(vbase0 + j * 64, lVw0);
    gld16(vbase1 + j * 64, lVw1);
    __syncthreads();

    f32x4 s[4] = {};
    #pragma unroll
    for (int ka = 0; ka < 2; ka++) {
      #pragma unroll
      for (int n = 0; n < 4; n++) {
        int row = n * 16 + (lane & 15);
        bf16x8 kb = *(const bf16x8*)((const char*)lK + row * 128 +
                                     (((ka * 4 + (lane >> 4)) ^ (row & 7)) * 16));
        s[n] = mfma16(qf[ka], kb, s[n]);
      }
    }
    if (j == qb) {
      int qrow = w * 16 + (lane >> 4) * 4;
      #pragma unroll
      for (int n = 0; n < 4; n++) {
        int key = n * 16 + (lane & 15);
        #pragma unroll
        for (int i = 0; i < 4; i++)
          if (key > qrow + i) s[n][i] = -__builtin_inff();
      }
    }
    float pm[4];
    #pragma unroll
    for (int i = 0; i < 4; i++) {
      float v = fmaxf(fmaxf(s[0][i], s[1][i]), fmaxf(s[2][i], s[3][i]));
      #pragma unroll
      for (int msk = 1; msk < 16; msk <<= 1) v = fmaxf(v, __shfl_xor(v, msk));
      pm[i] = v;
    }
    float ps[4];
    #pragma unroll
    for (int i = 0; i < 4; i++) {
      float mnew = fmaxf(mr[i], pm[i]);
      float sc = expf(mr[i] - mnew);
      mr[i] = mnew;
      lr[i] *= sc;
      #pragma unroll
      for (int t = 0; t < 4; t++) acc[t][i] *= sc;
      ps[i] = 0.f;
    }
    int c = lane & 15;
    int rlb = (lane >> 4) * 4;
    #pragma unroll
    for (int n = 0; n < 4; n++) {
      #pragma unroll
      for (int i = 0; i < 4; i++) {
        float p = expf(s[n][i] - mr[i]);
        u16 pb = f2b(p);
        int rl = rlb + i;
        int chunk = (n * 2 + (c >> 3)) ^ (rl & 7);
        *((u16*)((char*)lP[w] + rl * 128 + chunk * 16 + (c & 7) * 2)) = pb;
        ps[i] += b2f(pb);
      }
    }
    #pragma unroll
    for (int i = 0; i < 4; i++) {
      float v = ps[i];
      #pragma unroll
      for (int msk = 1; msk < 16; msk <<= 1) v += __shfl_xor(v, msk);
      lr[i] += v;
    }
    asm volatile("s_waitcnt lgkmcnt(0)" ::: "memory");
    __builtin_amdgcn_sched_barrier(0);
    #pragma unroll
    for (int ka = 0; ka < 2; ka++) {
      int prow = lane & 15;
      bf16x8 pa = *(const bf16x8*)((const char*)lP[w] + prow * 128 +
                                   (((ka * 4 + (lane >> 4)) ^ (prow & 7)) * 16));
      #pragma unroll
      for (int t = 0; t < 4; t++) {
        int vrow = t * 16 + (lane & 15);
        bf16x8 vb = *(const bf16x8*)((const char*)lV + vrow * 128 +
                                     (((ka * 4 + (lane >> 4)) ^ (vrow & 7)) * 16));
        acc[t] = mfma16(pa, vb, acc[t]);
      }
    }
    __syncthreads();
  }
  #pragma unroll
  for (int i = 0; i < 4; i++) {
    int qrow = qb * 64 + w * 16 + (lane >> 4) * 4 + i;
    float inv = 1.f / lr[i];
    #pragma unroll
    for (int t = 0; t < 4; t++) {
      size_t idx = ((size_t)b * T_ + qrow) * D_ + h * 64 + t * 16 + (lane & 15);
      X[idx] = xv[idx] + acc[t][i] * inv;
    }
  }
}

// ------------------------------- launch -------------------------------
extern "C" void kernel_launch(void* const* d_in, const int* in_sizes, int n_in,
                              void* d_out, int out_size, void* d_ws, size_t ws_size,
                              hipStream_t stream) {
  const int*   x_type   = (const int*)d_in[0];
  const float* x_value  = (const float*)d_in[1];
  const float* seq      = (const float*)d_in[2];
  const float* W_attn   = (const float*)d_in[3];
  const float* type_emb = (const float*)d_in[4];
  const float* ln1_g    = (const float*)d_in[5];
  const float* ln1_b    = (const float*)d_in[6];
  const float* ln2_g    = (const float*)d_in[7];
  const float* ln2_b    = (const float*)d_in[8];
  const float* W1       = (const float*)d_in[9];
  const float* b1       = (const float*)d_in[10];
  const float* W2       = (const float*)d_in[11];
  const float* b2       = (const float*)d_in[12];
  float* out = (float*)d_out;
  char* ws = (char*)d_ws;

  // workspace layout — total 40,370,176 B (~38.5 MiB)
  u16*   WtA  = (u16*)(ws + 0);             // 1536x512 bf16  1.5 MiB
  u16*   W1t  = (u16*)(ws + 1572864);       // 2048x512 bf16  2 MiB
  u16*   W2t  = (u16*)(ws + 3670016);       // 512x1024 bf16  1 MiB
  float* rqc  = (float*)(ws + 4718592);     // 4 rope tables, 512 KiB each
  float* rqs  = (float*)(ws + 5242880);
  float* rkc  = (float*)(ws + 5767168);
  float* rks  = (float*)(ws + 6291456);
  u16*   hbuf = (u16*)(ws + 6815744);       // 8192x512 bf16 (h, then h2)  8 MiB
  u16*   qTb  = (u16*)(ws + 15204352);      // (B,H,T,64) bf16  8 MiB
  u16*   kTb  = (u16*)(ws + 23592960);      // 8 MiB
  u16*   vTb  = (u16*)(ws + 31981568);      // (B,H,64,T) bf16  8 MiB
  u16*   ff1a = (u16*)(ws + 15204352);      // 8192x1024 bf16 16 MiB, aliases qT+kT (dead post-attn)

  transpose_cast<<<(1536 * 512 + 255) / 256, 256, 0, stream>>>(W_attn, WtA, 512, 1536);
  transpose_cast<<<(2048 * 512 + 255) / 256, 256, 0, stream>>>(W1, W1t, 512, 2048);
  transpose_cast<<<(512 * 1024 + 255) / 256, 256, 0, stream>>>(W2, W2t, 1024, 512);
  rope_tables<<<(B_ * T_ * 16) / 256, 256, 0, stream>>>(seq, rqc, rqs, rkc, rks);
  ln_kernel<<<B_ * T_, 256, 0, stream>>>(x_value, ln1_g, ln1_b, hbuf);
  gemm_qkv<<<dim3(12, 64), 256, 0, stream>>>(hbuf, WtA, x_type, type_emb,
                                             rqc, rqs, rkc, rks, qTb, kTb, vTb);
  attn_kernel<<<dim3(16, 64), 256, 0, stream>>>(qTb, kTb, vTb, x_value, out);
  ln_kernel<<<B_ * T_, 256, 0, stream>>>(out, ln2_g, ln2_b, hbuf);
  gemm_ff1<<<dim3(8, 64), 256, 0, stream>>>(hbuf, W1t, b1, ff1a);
  gemm_ff2<<<dim3(4, 64), 256, 0, stream>>>(ff1a, W2t, b2, out);
}

// Round 3
// 189.140 us; speedup vs baseline: 1.2523x; 1.2523x over previous
//
#include <hip/hip_runtime.h>
#include <stdint.h>
#include <math.h>

typedef unsigned short u16;
typedef unsigned int u32;
typedef __attribute__((ext_vector_type(8))) short bf16x8;   // 8 bf16 (4 VGPRs) MFMA A/B frag
typedef __attribute__((ext_vector_type(4))) float f32x4;
typedef __attribute__((ext_vector_type(2))) float f32x2;
typedef __attribute__((ext_vector_type(2))) u16 u16x2;
typedef __attribute__((ext_vector_type(8))) u16 u16x8;

#define B_ 8
#define T_ 1024
#define D_ 512
#define H_ 8
#define TP1 1025
// q scale: 1/sqrt(64) * log2(e)  (softmax runs in exp2 domain)
#define QSCALE 0.1803368801111204f

__device__ __forceinline__ u16 f2b(float f) {           // f32 -> bf16 RNE
  union { float f; u32 u; } v; v.f = f;
  return (u16)((v.u + 0x7fffu + ((v.u >> 16) & 1u)) >> 16);
}
__device__ __forceinline__ float b2f(u16 b) {
  union { u32 u; float f; } v; v.u = ((u32)b) << 16; return v.f;
}
__device__ __forceinline__ void gld16(const void* g, void* l) {
  // async global->LDS, 16B/lane; LDS dest = wave-uniform base + lane*16
  __builtin_amdgcn_global_load_lds((const __attribute__((address_space(1))) u32*)g,
                                   (__attribute__((address_space(3))) u32*)l, 16, 0, 0);
}
__device__ __forceinline__ f32x4 mfma16(bf16x8 a, bf16x8 b, f32x4 c) {
  return __builtin_amdgcn_mfma_f32_16x16x32_bf16(a, b, c, 0, 0, 0);
}

// ---------------- weight transpose + cast: Wt[n][k] = bf16(W[k][n]) ----------------
__global__ __launch_bounds__(256) void transpose_cast(const float* __restrict__ W,
                                                      u16* __restrict__ Wt, int K, int N) {
  int i = blockIdx.x * 256 + threadIdx.x;
  if (i >= K * N) return;
  int n = i / K, k = i % K;
  Wt[i] = f2b(W[(size_t)k * N + n]);
}

// ---------------- RoPE tables: cos/sin for q (pos[t]) and k (pos[t+1]) ----------------
__global__ __launch_bounds__(256) void rope_tables(const float* __restrict__ seq,
    float* __restrict__ cq, float* __restrict__ sq,
    float* __restrict__ ck, float* __restrict__ sk) {
  int i = blockIdx.x * 256 + threadIdx.x;      // B*T*16
  if (i >= B_ * T_ * 16) return;
  int p = i & 15, bt = i >> 4, b = bt >> 10, t = bt & 1023;
  float inv = expf(-(float)p * 0.5756462732485115f);   // 10000^(-p/16)
  float aq = seq[b * TP1 + t] * inv;
  float ak = seq[b * TP1 + t + 1] * inv;
  cq[i] = cosf(aq); sq[i] = sinf(aq);
  ck[i] = cosf(ak); sk[i] = sinf(ak);
}

// ---------------- LayerNorm row kernel: f32 in -> bf16 out ----------------
__global__ __launch_bounds__(256) void ln_kernel(const float* __restrict__ x,
    const float* __restrict__ g, const float* __restrict__ bta, u16* __restrict__ out) {
  int row = blockIdx.x;                       // 8192 rows
  int tid = threadIdx.x;
  const float* xr = x + (size_t)row * D_;
  f32x2 v = *(const f32x2*)(xr + tid * 2);
  float s = v[0] + v[1];
  float sq = v[0] * v[0] + v[1] * v[1];
  #pragma unroll
  for (int m = 32; m; m >>= 1) { s += __shfl_down(s, m); sq += __shfl_down(sq, m); }
  __shared__ float ls[4], lq[4];
  int w = tid >> 6, lane = tid & 63;
  if (lane == 0) { ls[w] = s; lq[w] = sq; }
  __syncthreads();
  if (tid == 0) {
    float a = ls[0] + ls[1] + ls[2] + ls[3];
    float c = lq[0] + lq[1] + lq[2] + lq[3];
    ls[0] = a; lq[0] = c;
  }
  __syncthreads();
  float mean = ls[0] * (1.f / D_);
  float var = lq[0] * (1.f / D_) - mean * mean;
  float rstd = rsqrtf(var + 1e-5f);
  float g0 = g[2 * tid], g1 = g[2 * tid + 1];
  float b0 = bta[2 * tid], b1v = bta[2 * tid + 1];
  u16x2 o;
  o[0] = f2b((v[0] - mean) * rstd * g0 + b0);
  o[1] = f2b((v[1] - mean) * rstd * g1 + b1v);
  *(u16x2*)(out + (size_t)row * D_ + tid * 2) = o;
}

// ============ GEMM tiles: 128x128, BK=32, double-buffered 2-phase staging ============
// staging swizzle: stored[row][p] = global chunk p ^ s(row), s(row)=(row>>1)&3
// read chunk g at position g ^ s(row) -> 2-way bank aliasing only (free, m136).

// ---------------- QKV GEMM with fused type-emb + RoPE + scale + head-layout epilogue ----------------
__global__ __launch_bounds__(256) void gemm_qkv(const u16* __restrict__ A,
    const u16* __restrict__ Bt,
    const int* __restrict__ x_type, const float* __restrict__ type_emb,
    const float* __restrict__ rqc, const float* __restrict__ rqs,
    const float* __restrict__ rkc, const float* __restrict__ rks,
    u16* __restrict__ qT, u16* __restrict__ kT, u16* __restrict__ vT) {
  __shared__ u16 lA[2][4096];
  __shared__ u16 lB[2][4096];
  const int K = 512;
  const int tid = threadIdx.x, lane = tid & 63, w = tid >> 6;
  const int wm = w >> 1, wn = w & 1;
  const size_t bm = (size_t)blockIdx.y * 128;
  const size_t bn = (size_t)blockIdx.x * 128;

  const int r0 = tid >> 2;
  const int cs = ((tid & 3) ^ ((r0 >> 1) & 3)) * 8;
  const u16* a0 = A + (bm + r0) * K + cs;
  const u16* a1 = A + (bm + 64 + r0) * K + cs;
  const u16* b0 = Bt + (bn + r0) * K + cs;
  const u16* b1p = Bt + (bn + 64 + r0) * K + cs;

  int aoff[4], boff[4];
  #pragma unroll
  for (int i = 0; i < 4; i++) {
    int ra = wm * 64 + i * 16 + (lane & 15);
    aoff[i] = ra * 64 + (((lane >> 4) ^ ((ra >> 1) & 3)) * 16);
    int rb = wn * 64 + i * 16 + (lane & 15);
    boff[i] = rb * 64 + (((lane >> 4) ^ ((rb >> 1) & 3)) * 16);
  }

  auto stage = [&](int k0, int buf) {
    char* ad = (char*)lA + buf * 8192 + w * 1024;
    char* bd = (char*)lB + buf * 8192 + w * 1024;
    gld16(a0 + k0, ad);
    gld16(a1 + k0, ad + 4096);
    gld16(b0 + k0, bd);
    gld16(b1p + k0, bd + 4096);
  };

  f32x4 acc[4][4] = {};
  stage(0, 0);
  __syncthreads();
  int cur = 0;
  for (int k0 = 0; k0 < K; k0 += 32) {
    if (k0 + 32 < K) stage(k0 + 32, cur ^ 1);     // prefetch overlaps compute below
    const char* lAc = (const char*)lA + cur * 8192;
    const char* lBc = (const char*)lB + cur * 8192;
    bf16x8 af[4], bf[4];
    #pragma unroll
    for (int i = 0; i < 4; i++) af[i] = *(const bf16x8*)(lAc + aoff[i]);
    #pragma unroll
    for (int n = 0; n < 4; n++) bf[n] = *(const bf16x8*)(lBc + boff[n]);
    __builtin_amdgcn_s_setprio(1);
    #pragma unroll
    for (int i = 0; i < 4; i++)
      #pragma unroll
      for (int n = 0; n < 4; n++)
        acc[i][n] = mfma16(af[i], bf[n], acc[i][n]);
    __builtin_amdgcn_s_setprio(0);
    __syncthreads();                              // drains prefetch; publishes buf cur^1
    cur ^= 1;
  }

  // fused epilogue. block-uniform region: 0=q (cols 0..511), 1=k, 2=v
  const int region = (int)(bn >> 9);
  #pragma unroll
  for (int i = 0; i < 4; i++) {
    #pragma unroll
    for (int jj = 0; jj < 4; jj++) {
      int row = (int)bm + wm * 64 + i * 16 + (lane >> 4) * 4 + jj;   // bt index
      int b = row >> 10, t = row & 1023;
      if (region == 0) {
        int ty = x_type[b * TP1 + t];
        #pragma unroll
        for (int n = 0; n < 4; n++) {
          int cloc = (int)bn + wn * 64 + n * 16 + (lane & 15);       // 0..511
          int h = cloc >> 6, hd = cloc & 63;
          float v = acc[i][n][jj] + type_emb[(size_t)ty * 1024 + cloc];
          float vp = __shfl_xor(v, 1);
          if (hd < 32) {
            int p = hd >> 1;
            float c = rqc[row * 16 + p], s = rqs[row * 16 + p];
            v = (hd & 1) ? (v * c + vp * s) : (v * c - vp * s);
          }
          qT[((size_t)(b * 8 + h) * T_ + t) * 64 + hd] = f2b(v * QSCALE);
        }
      } else if (region == 1) {
        int ty = x_type[b * TP1 + t + 1];
        #pragma unroll
        for (int n = 0; n < 4; n++) {
          int cloc = (int)bn - 512 + wn * 64 + n * 16 + (lane & 15); // 0..511
          int h = cloc >> 6, hd = cloc & 63;
          float v = acc[i][n][jj] + type_emb[(size_t)ty * 1024 + 512 + cloc];
          float vp = __shfl_xor(v, 1);
          if (hd < 32) {
            int p = hd >> 1;
            float c = rkc[row * 16 + p], s = rks[row * 16 + p];
            v = (hd & 1) ? (v * c + vp * s) : (v * c - vp * s);
          }
          kT[((size_t)(b * 8 + h) * T_ + t) * 64 + hd] = f2b(v);
        }
      } else {
        #pragma unroll
        for (int n = 0; n < 4; n++) {
          int cloc = (int)bn - 1024 + wn * 64 + n * 16 + (lane & 15);
          int h = cloc >> 6, hd = cloc & 63;
          vT[((size_t)(b * 8 + h) * 64 + hd) * T_ + t] = f2b(acc[i][n][jj]);
        }
      }
    }
  }
}

// ---------------- FF1 GEMM with fused bias + SwiGLU epilogue -> bf16 ----------------
__global__ __launch_bounds__(256) void gemm_ff1(const u16* __restrict__ A,
    const u16* __restrict__ Bt, const float* __restrict__ b1,
    u16* __restrict__ outp) {
  __shared__ u16 lA[2][4096];
  __shared__ u16 lBa[2][4096];
  __shared__ u16 lBg[2][4096];
  const int K = 512;
  const int tid = threadIdx.x, lane = tid & 63, w = tid >> 6;
  const int wm = w >> 1, wn = w & 1;
  const size_t bm = (size_t)blockIdx.y * 128;
  const size_t bn = (size_t)blockIdx.x * 128;

  const int r0 = tid >> 2;
  const int cs = ((tid & 3) ^ ((r0 >> 1) & 3)) * 8;
  const u16* a0  = A + (bm + r0) * K + cs;
  const u16* a1  = A + (bm + 64 + r0) * K + cs;
  const u16* ba0 = Bt + (bn + r0) * K + cs;
  const u16* ba1 = Bt + (bn + 64 + r0) * K + cs;
  const u16* bg0 = Bt + (1024 + bn + r0) * K + cs;
  const u16* bg1 = Bt + (1024 + bn + 64 + r0) * K + cs;

  int aoff[4], boff[4];
  #pragma unroll
  for (int i = 0; i < 4; i++) {
    int ra = wm * 64 + i * 16 + (lane & 15);
    aoff[i] = ra * 64 + (((lane >> 4) ^ ((ra >> 1) & 3)) * 16);
    int rb = wn * 64 + i * 16 + (lane & 15);
    boff[i] = rb * 64 + (((lane >> 4) ^ ((rb >> 1) & 3)) * 16);
  }

  auto stage = [&](int k0, int buf) {
    char* ad  = (char*)lA  + buf * 8192 + w * 1024;
    char* bad = (char*)lBa + buf * 8192 + w * 1024;
    char* bgd = (char*)lBg + buf * 8192 + w * 1024;
    gld16(a0 + k0, ad);
    gld16(a1 + k0, ad + 4096);
    gld16(ba0 + k0, bad);
    gld16(ba1 + k0, bad + 4096);
    gld16(bg0 + k0, bgd);
    gld16(bg1 + k0, bgd + 4096);
  };

  f32x4 aca[4][4] = {}, acg[4][4] = {};
  stage(0, 0);
  __syncthreads();
  int cur = 0;
  for (int k0 = 0; k0 < K; k0 += 32) {
    if (k0 + 32 < K) stage(k0 + 32, cur ^ 1);
    const char* lAc  = (const char*)lA  + cur * 8192;
    const char* lBac = (const char*)lBa + cur * 8192;
    const char* lBgc = (const char*)lBg + cur * 8192;
    bf16x8 af[4], bfa[4], bfg[4];
    #pragma unroll
    for (int i = 0; i < 4; i++) af[i]  = *(const bf16x8*)(lAc  + aoff[i]);
    #pragma unroll
    for (int n = 0; n < 4; n++) bfa[n] = *(const bf16x8*)(lBac + boff[n]);
    #pragma unroll
    for (int n = 0; n < 4; n++) bfg[n] = *(const bf16x8*)(lBgc + boff[n]);
    __builtin_amdgcn_s_setprio(1);
    #pragma unroll
    for (int i = 0; i < 4; i++) {
      #pragma unroll
      for (int n = 0; n < 4; n++) {
        aca[i][n] = mfma16(af[i], bfa[n], aca[i][n]);
        acg[i][n] = mfma16(af[i], bfg[n], acg[i][n]);
      }
    }
    __builtin_amdgcn_s_setprio(0);
    __syncthreads();
    cur ^= 1;
  }
  #pragma unroll
  for (int i = 0; i < 4; i++) {
    #pragma unroll
    for (int n = 0; n < 4; n++) {
      int col = (int)bn + wn * 64 + n * 16 + (lane & 15);
      float bav = b1[col], bgv = b1[1024 + col];
      #pragma unroll
      for (int jj = 0; jj < 4; jj++) {
        int row = (int)bm + wm * 64 + i * 16 + (lane >> 4) * 4 + jj;
        float av = aca[i][n][jj] + bav;
        float gv = acg[i][n][jj] + bgv;
        float sg = gv / (1.f + expf(-gv));
        outp[(size_t)row * 1024 + col] = f2b(sg * av);
      }
    }
  }
}

// ---------------- FF2 GEMM, 512 thr / 8 waves (2 waves/SIMD at 1 block/CU) ----------------
__global__ __launch_bounds__(512) void gemm_ff2(const u16* __restrict__ A,
    const u16* __restrict__ Bt, const float* __restrict__ bias,
    float* __restrict__ C) {
  __shared__ u16 lA[2][4096];
  __shared__ u16 lB[2][4096];
  const int K = 1024, N = 512;
  const int tid = threadIdx.x, lane = tid & 63, w = tid >> 6;   // w 0..7
  const int wm = w >> 2, wn = w & 3;                            // 2x4 waves: 64x32 each
  const size_t bm = (size_t)blockIdx.y * 128;
  const size_t bn = (size_t)blockIdx.x * 128;

  const int r0 = tid >> 2;                                      // 0..127
  const int cs = ((tid & 3) ^ ((r0 >> 1) & 3)) * 8;
  const u16* a0 = A + (bm + r0) * K + cs;
  const u16* b0 = Bt + (bn + r0) * K + cs;

  int aoff[4], boff[2];
  #pragma unroll
  for (int i = 0; i < 4; i++) {
    int ra = wm * 64 + i * 16 + (lane & 15);
    aoff[i] = ra * 64 + (((lane >> 4) ^ ((ra >> 1) & 3)) * 16);
  }
  #pragma unroll
  for (int n = 0; n < 2; n++) {
    int rb = wn * 32 + n * 16 + (lane & 15);
    boff[n] = rb * 64 + (((lane >> 4) ^ ((rb >> 1) & 3)) * 16);
  }

  auto stage = [&](int k0, int buf) {      // 512 thr: one call covers full 8KB tile
    gld16(a0 + k0, (char*)lA + buf * 8192 + w * 1024);
    gld16(b0 + k0, (char*)lB + buf * 8192 + w * 1024);
  };

  f32x4 acc[4][2] = {};
  stage(0, 0);
  __syncthreads();
  int cur = 0;
  for (int k0 = 0; k0 < K; k0 += 32) {
    if (k0 + 32 < K) stage(k0 + 32, cur ^ 1);
    const char* lAc = (const char*)lA + cur * 8192;
    const char* lBc = (const char*)lB + cur * 8192;
    bf16x8 af[4], bf[2];
    #pragma unroll
    for (int i = 0; i < 4; i++) af[i] = *(const bf16x8*)(lAc + aoff[i]);
    #pragma unroll
    for (int n = 0; n < 2; n++) bf[n] = *(const bf16x8*)(lBc + boff[n]);
    __builtin_amdgcn_s_setprio(1);
    #pragma unroll
    for (int i = 0; i < 4; i++)
      #pragma unroll
      for (int n = 0; n < 2; n++)
        acc[i][n] = mfma16(af[i], bf[n], acc[i][n]);
    __builtin_amdgcn_s_setprio(0);
    __syncthreads();
    cur ^= 1;
  }
  #pragma unroll
  for (int i = 0; i < 4; i++) {
    size_t mrow = bm + wm * 64 + i * 16 + (lane >> 4) * 4;
    #pragma unroll
    for (int n = 0; n < 2; n++) {
      size_t col = bn + wn * 32 + n * 16 + (lane & 15);
      float bv = bias[col];
      #pragma unroll
      for (int jj = 0; jj < 4; jj++) {
        size_t idx = (mrow + jj) * (size_t)N + col;
        C[idx] = acc[i][n][jj] + bv + C[idx];   // in-place residual
      }
    }
  }
}

// ---------------- causal flash attention + residual: out = x_value + attn ----------------
// 2-phase double-buffered K/V staging; exp2-domain softmax; defer-max THR=8.
__global__ __launch_bounds__(256) void attn_kernel(const u16* __restrict__ qT,
    const u16* __restrict__ kT, const u16* __restrict__ vT,
    const float* __restrict__ xv, float* __restrict__ X) {
  const int qb = 15 - blockIdx.x;          // LPT: longest causal blocks dispatch first
  const int bh = blockIdx.y;
  const int b = bh >> 3, h = bh & 7;
  const int tid = threadIdx.x, lane = tid & 63, w = tid >> 6;
  __shared__ u16 lK[2][4096];
  __shared__ u16 lV[2][4096];
  __shared__ u16 lP[4][1024];

  bf16x8 qf[2];
  {
    int row = qb * 64 + w * 16 + (lane & 15);
    const u16* qp = qT + ((size_t)bh * T_ + row) * 64 + (lane >> 4) * 8;
    qf[0] = *(const bf16x8*)qp;
    qf[1] = *(const bf16x8*)(qp + 32);
  }
  f32x4 acc[4] = {};
  float mr[4], lr[4] = {};
  #pragma unroll
  for (int i = 0; i < 4; i++) mr[i] = -__builtin_inff();

  const int sr = tid >> 3;
  const int scs = ((tid & 7) ^ (sr & 7)) * 8;
  const u16* kb0 = kT + ((size_t)bh * T_ + sr) * 64 + scs;
  const u16* kb1 = kT + ((size_t)bh * T_ + 32 + sr) * 64 + scs;
  const u16* vb0 = vT + ((size_t)bh * 64 + sr) * T_ + scs;
  const u16* vb1 = vT + ((size_t)bh * 64 + 32 + sr) * T_ + scs;

  auto stage = [&](int j, int buf) {
    char* kd = (char*)lK + buf * 8192 + w * 1024;
    char* vd = (char*)lV + buf * 8192 + w * 1024;
    gld16(kb0 + (size_t)j * 4096, kd);
    gld16(kb1 + (size_t)j * 4096, kd + 4096);
    gld16(vb0 + j * 64, vd);
    gld16(vb1 + j * 64, vd + 4096);
  };

  stage(0, 0);
  __syncthreads();
  int cur = 0;
  for (int j = 0; j <= qb; j++) {
    if (j < qb) stage(j + 1, cur ^ 1);     // prefetch next tile under compute
    const char* lKc = (const char*)lK + cur * 8192;
    const char* lVc = (const char*)lV + cur * 8192;

    f32x4 s[4] = {};
    __builtin_amdgcn_s_setprio(1);
    #pragma unroll
    for (int ka = 0; ka < 2; ka++) {
      #pragma unroll
      for (int n = 0; n < 4; n++) {
        int row = n * 16 + (lane & 15);
        bf16x8 kb = *(const bf16x8*)(lKc + row * 128 +
                                     (((ka * 4 + (lane >> 4)) ^ (row & 7)) * 16));
        s[n] = mfma16(qf[ka], kb, s[n]);
      }
    }
    __builtin_amdgcn_s_setprio(0);
    if (j == qb) {                          // causal mask on diagonal block
      int qrow = w * 16 + (lane >> 4) * 4;
      #pragma unroll
      for (int n = 0; n < 4; n++) {
        int key = n * 16 + (lane & 15);
        #pragma unroll
        for (int i = 0; i < 4; i++)
          if (key > qrow + i) s[n][i] = -__builtin_inff();
      }
    }
    float pm[4];
    #pragma unroll
    for (int i = 0; i < 4; i++) {
      float v = fmaxf(fmaxf(s[0][i], s[1][i]), fmaxf(s[2][i], s[3][i]));
      #pragma unroll
      for (int msk = 1; msk < 16; msk <<= 1) v = fmaxf(v, __shfl_xor(v, msk));
      pm[i] = v;
    }
    bool need = false;
    #pragma unroll
    for (int i = 0; i < 4; i++) need |= (pm[i] > mr[i] + 8.f);
    if (__any(need)) {                      // defer-max: skip rescale when growth < 2^8
      #pragma unroll
      for (int i = 0; i < 4; i++) {
        float mnew = fmaxf(mr[i], pm[i]);
        float sc = exp2f(mr[i] - mnew);
        mr[i] = mnew;
        lr[i] *= sc;
        #pragma unroll
        for (int t = 0; t < 4; t++) acc[t][i] *= sc;
      }
    }
    float ps[4] = {};
    int c = lane & 15;
    int rlb = (lane >> 4) * 4;
    #pragma unroll
    for (int n = 0; n < 4; n++) {
      #pragma unroll
      for (int i = 0; i < 4; i++) {
        float p = exp2f(s[n][i] - mr[i]);
        u16 pb = f2b(p);
        int rl = rlb + i;
        int chunk = (n * 2 + (c >> 3)) ^ (rl & 7);
        *((u16*)((char*)lP[w] + rl * 128 + chunk * 16 + (c & 7) * 2)) = pb;
        ps[i] += b2f(pb);
      }
    }
    #pragma unroll
    for (int i = 0; i < 4; i++) {
      float v = ps[i];
      #pragma unroll
      for (int msk = 1; msk < 16; msk <<= 1) v += __shfl_xor(v, msk);
      lr[i] += v;
    }
    asm volatile("s_waitcnt lgkmcnt(0)" ::: "memory");
    __builtin_amdgcn_sched_barrier(0);
    __builtin_amdgcn_s_setprio(1);
    #pragma unroll
    for (int ka = 0; ka < 2; ka++) {
      int prow = lane & 15;
      bf16x8 pa = *(const bf16x8*)((const char*)lP[w] + prow * 128 +
                                   (((ka * 4 + (lane >> 4)) ^ (prow & 7)) * 16));
      #pragma unroll
      for (int t = 0; t < 4; t++) {
        int vrow = t * 16 + (lane & 15);
        bf16x8 vb = *(const bf16x8*)(lVc + vrow * 128 +
                                     (((ka * 4 + (lane >> 4)) ^ (vrow & 7)) * 16));
        acc[t] = mfma16(pa, vb, acc[t]);
      }
    }
    __builtin_amdgcn_s_setprio(0);
    __syncthreads();                        // drains prefetch; publishes buf cur^1
    cur ^= 1;
  }
  #pragma unroll
  for (int i = 0; i < 4; i++) {
    int qrow = qb * 64 + w * 16 + (lane >> 4) * 4 + i;
    float inv = 1.f / lr[i];
    #pragma unroll
    for (int t = 0; t < 4; t++) {
      size_t idx = ((size_t)b * T_ + qrow) * D_ + h * 64 + t * 16 + (lane & 15);
      X[idx] = xv[idx] + acc[t][i] * inv;
    }
  }
}

// ------------------------------- launch -------------------------------
extern "C" void kernel_launch(void* const* d_in, const int* in_sizes, int n_in,
                              void* d_out, int out_size, void* d_ws, size_t ws_size,
                              hipStream_t stream) {
  const int*   x_type   = (const int*)d_in[0];
  const float* x_value  = (const float*)d_in[1];
  const float* seq      = (const float*)d_in[2];
  const float* W_attn   = (const float*)d_in[3];
  const float* type_emb = (const float*)d_in[4];
  const float* ln1_g    = (const float*)d_in[5];
  const float* ln1_b    = (const float*)d_in[6];
  const float* ln2_g    = (const float*)d_in[7];
  const float* ln2_b    = (const float*)d_in[8];
  const float* W1       = (const float*)d_in[9];
  const float* b1       = (const float*)d_in[10];
  const float* W2       = (const float*)d_in[11];
  const float* b2       = (const float*)d_in[12];
  float* out = (float*)d_out;
  char* ws = (char*)d_ws;

  // workspace layout — total ~38.5 MiB
  u16*   WtA  = (u16*)(ws + 0);             // 1536x512 bf16  1.5 MiB
  u16*   W1t  = (u16*)(ws + 1572864);       // 2048x512 bf16  2 MiB
  u16*   W2t  = (u16*)(ws + 3670016);       // 512x1024 bf16  1 MiB
  float* rqc  = (float*)(ws + 4718592);     // 4 rope tables, 512 KiB each
  float* rqs  = (float*)(ws + 5242880);
  float* rkc  = (float*)(ws + 5767168);
  float* rks  = (float*)(ws + 6291456);
  u16*   hbuf = (u16*)(ws + 6815744);       // 8192x512 bf16 (h, then h2)  8 MiB
  u16*   qTb  = (u16*)(ws + 15204352);      // (B,H,T,64) bf16  8 MiB
  u16*   kTb  = (u16*)(ws + 23592960);      // 8 MiB
  u16*   vTb  = (u16*)(ws + 31981568);      // (B,H,64,T) bf16  8 MiB
  u16*   ff1a = (u16*)(ws + 15204352);      // 8192x1024 bf16 16 MiB, aliases qT+kT (dead post-attn)

  transpose_cast<<<(1536 * 512 + 255) / 256, 256, 0, stream>>>(W_attn, WtA, 512, 1536);
  transpose_cast<<<(2048 * 512 + 255) / 256, 256, 0, stream>>>(W1, W1t, 512, 2048);
  transpose_cast<<<(512 * 1024 + 255) / 256, 256, 0, stream>>>(W2, W2t, 1024, 512);
  rope_tables<<<(B_ * T_ * 16) / 256, 256, 0, stream>>>(seq, rqc, rqs, rkc, rks);
  ln_kernel<<<B_ * T_, 256, 0, stream>>>(x_value, ln1_g, ln1_b, hbuf);
  gemm_qkv<<<dim3(12, 64), 256, 0, stream>>>(hbuf, WtA, x_type, type_emb,
                                             rqc, rqs, rkc, rks, qTb, kTb, vTb);
  attn_kernel<<<dim3(16, 64), 256, 0, stream>>>(qTb, kTb, vTb, x_value, out);
  ln_kernel<<<B_ * T_, 256, 0, stream>>>(out, ln2_g, ln2_b, hbuf);
  gemm_ff1<<<dim3(8, 64), 256, 0, stream>>>(hbuf, W1t, b1, ff1a);
  gemm_ff2<<<dim3(4, 64), 512, 0, stream>>>(ff1a, W2t, b2, out);
}

// Round 4
// 177.586 us; speedup vs baseline: 1.3338x; 1.0651x over previous
//
#include <hip/hip_runtime.h>
#include <stdint.h>
#include <math.h>

typedef unsigned short u16;
typedef unsigned int u32;
typedef __attribute__((ext_vector_type(8))) short bf16x8;   // 8 bf16 (4 VGPRs) MFMA A/B frag
typedef __attribute__((ext_vector_type(4))) float f32x4;
typedef __attribute__((ext_vector_type(2))) float f32x2;
typedef __attribute__((ext_vector_type(2))) u16 u16x2;
typedef __attribute__((ext_vector_type(8))) u16 u16x8;
typedef __attribute__((ext_vector_type(2))) u32 u32x2;

#define B_ 8
#define T_ 1024
#define D_ 512
#define H_ 8
#define TP1 1025
// q scale: 1/sqrt(64) * log2(e)  (softmax runs in exp2 domain)
#define QSCALE 0.1803368801111204f

__device__ __forceinline__ u16 f2b(float f) {           // f32 -> bf16 RNE
  union { float f; u32 u; } v; v.f = f;
  return (u16)((v.u + 0x7fffu + ((v.u >> 16) & 1u)) >> 16);
}
__device__ __forceinline__ void gld16(const void* g, void* l) {
  // async global->LDS, 16B/lane; LDS dest = wave-uniform base + lane*16
  __builtin_amdgcn_global_load_lds((const __attribute__((address_space(1))) u32*)g,
                                   (__attribute__((address_space(3))) u32*)l, 16, 0, 0);
}
__device__ __forceinline__ f32x4 mfma16(bf16x8 a, bf16x8 b, f32x4 c) {
  return __builtin_amdgcn_mfma_f32_16x16x32_bf16(a, b, c, 0, 0, 0);
}
__device__ __forceinline__ u32 cvtpk(float lo, float hi) {   // 2xf32 -> packed bf16x2 (RNE)
  u32 r;
  asm("v_cvt_pk_bf16_f32 %0, %1, %2" : "=v"(r) : "v"(lo), "v"(hi));
  return r;
}
union U8 { u32 u[4]; bf16x8 v; };

// ---------------- weight transpose + cast: Wt[n][k] = bf16(W[k][n]) ----------------
__global__ __launch_bounds__(256) void transpose_cast(const float* __restrict__ W,
                                                      u16* __restrict__ Wt, int K, int N) {
  int i = blockIdx.x * 256 + threadIdx.x;
  if (i >= K * N) return;
  int n = i / K, k = i % K;
  Wt[i] = f2b(W[(size_t)k * N + n]);
}

// ---------------- RoPE tables: cos/sin for q (pos[t]) and k (pos[t+1]) ----------------
__global__ __launch_bounds__(256) void rope_tables(const float* __restrict__ seq,
    float* __restrict__ cq, float* __restrict__ sq,
    float* __restrict__ ck, float* __restrict__ sk) {
  int i = blockIdx.x * 256 + threadIdx.x;      // B*T*16
  if (i >= B_ * T_ * 16) return;
  int p = i & 15, bt = i >> 4, b = bt >> 10, t = bt & 1023;
  float inv = expf(-(float)p * 0.5756462732485115f);   // 10000^(-p/16)
  float aq = seq[b * TP1 + t] * inv;
  float ak = seq[b * TP1 + t + 1] * inv;
  cq[i] = cosf(aq); sq[i] = sinf(aq);
  ck[i] = cosf(ak); sk[i] = sinf(ak);
}

// ---------------- LayerNorm: one WAVE per row, no LDS, no barriers ----------------
__global__ __launch_bounds__(256) void ln_kernel(const float* __restrict__ x,
    const float* __restrict__ g, const float* __restrict__ bta, u16* __restrict__ out) {
  int row = blockIdx.x * 4 + (threadIdx.x >> 6);    // 8192 rows, 4 rows/block
  int lane = threadIdx.x & 63;
  const float* xr = x + (size_t)row * D_ + lane * 8;
  f32x4 v0 = *(const f32x4*)xr;
  f32x4 v1 = *(const f32x4*)(xr + 4);
  float s = 0.f, sq = 0.f;
  #pragma unroll
  for (int j = 0; j < 4; j++) { s += v0[j] + v1[j]; sq += v0[j] * v0[j] + v1[j] * v1[j]; }
  #pragma unroll
  for (int m = 1; m < 64; m <<= 1) { s += __shfl_xor(s, m); sq += __shfl_xor(sq, m); }
  float mean = s * (1.f / D_);
  float var = sq * (1.f / D_) - mean * mean;
  float rstd = rsqrtf(var + 1e-5f);
  f32x4 g0 = *(const f32x4*)(g + lane * 8);
  f32x4 g1 = *(const f32x4*)(g + lane * 8 + 4);
  f32x4 b0 = *(const f32x4*)(bta + lane * 8);
  f32x4 b1 = *(const f32x4*)(bta + lane * 8 + 4);
  u16x8 o;
  #pragma unroll
  for (int j = 0; j < 4; j++) {
    o[j]     = f2b((v0[j] - mean) * rstd * g0[j] + b0[j]);
    o[4 + j] = f2b((v1[j] - mean) * rstd * g1[j] + b1[j]);
  }
  *(u16x8*)(out + (size_t)row * D_ + lane * 8) = o;
}

// ============ GEMM tiles: 128x128, BK=32, double-buffered, XCD-remapped 1-D grid ============
// staging swizzle: stored[row][p] = global chunk p ^ s(row), s(row)=(row>>1)&3

// ---------------- QKV GEMM with fused type-emb + RoPE + scale + head-layout epilogue ----------------
__global__ __launch_bounds__(256) void gemm_qkv(const u16* __restrict__ A,
    const u16* __restrict__ Bt,
    const int* __restrict__ x_type, const float* __restrict__ type_emb,
    const float* __restrict__ rqc, const float* __restrict__ rqs,
    const float* __restrict__ rkc, const float* __restrict__ rks,
    u16* __restrict__ qT, u16* __restrict__ kT, u16* __restrict__ vT) {
  __shared__ u16 lA[2][4096];
  __shared__ u16 lB[2][4096];
  const int K = 512;
  const int tid = threadIdx.x, lane = tid & 63, w = tid >> 6;
  const int wm = w >> 1, wn = w & 1;
  // XCD remap: 768 blocks -> each XCD gets 8 contiguous row-panels (A reuse in its L2)
  int swz = (blockIdx.x & 7) * 96 + (blockIdx.x >> 3);
  int byy = swz / 12, bxx = swz - byy * 12;
  const size_t bm = (size_t)byy * 128;
  const size_t bn = (size_t)bxx * 128;

  const int r0 = tid >> 2;
  const int cs = ((tid & 3) ^ ((r0 >> 1) & 3)) * 8;
  const u16* a0 = A + (bm + r0) * K + cs;
  const u16* a1 = A + (bm + 64 + r0) * K + cs;
  const u16* b0 = Bt + (bn + r0) * K + cs;
  const u16* b1p = Bt + (bn + 64 + r0) * K + cs;

  int aoff[4], boff[4];
  #pragma unroll
  for (int i = 0; i < 4; i++) {
    int ra = wm * 64 + i * 16 + (lane & 15);
    aoff[i] = ra * 64 + (((lane >> 4) ^ ((ra >> 1) & 3)) * 16);
    int rb = wn * 64 + i * 16 + (lane & 15);
    boff[i] = rb * 64 + (((lane >> 4) ^ ((rb >> 1) & 3)) * 16);
  }

  auto stage = [&](int k0, int buf) {
    char* ad = (char*)lA + buf * 8192 + w * 1024;
    char* bd = (char*)lB + buf * 8192 + w * 1024;
    gld16(a0 + k0, ad);
    gld16(a1 + k0, ad + 4096);
    gld16(b0 + k0, bd);
    gld16(b1p + k0, bd + 4096);
  };

  f32x4 acc[4][4] = {};
  stage(0, 0);
  __syncthreads();
  int cur = 0;
  for (int k0 = 0; k0 < K; k0 += 32) {
    if (k0 + 32 < K) stage(k0 + 32, cur ^ 1);     // prefetch overlaps compute below
    const char* lAc = (const char*)lA + cur * 8192;
    const char* lBc = (const char*)lB + cur * 8192;
    bf16x8 af[4], bf[4];
    #pragma unroll
    for (int i = 0; i < 4; i++) af[i] = *(const bf16x8*)(lAc + aoff[i]);
    #pragma unroll
    for (int n = 0; n < 4; n++) bf[n] = *(const bf16x8*)(lBc + boff[n]);
    __builtin_amdgcn_s_setprio(1);
    #pragma unroll
    for (int i = 0; i < 4; i++)
      #pragma unroll
      for (int n = 0; n < 4; n++)
        acc[i][n] = mfma16(af[i], bf[n], acc[i][n]);
    __builtin_amdgcn_s_setprio(0);
    __syncthreads();
    cur ^= 1;
  }

  // fused epilogue. block-uniform region: 0=q (cols 0..511), 1=k, 2=v
  const int region = (int)(bn >> 9);
  #pragma unroll
  for (int i = 0; i < 4; i++) {
    #pragma unroll
    for (int jj = 0; jj < 4; jj++) {
      int row = (int)bm + wm * 64 + i * 16 + (lane >> 4) * 4 + jj;   // bt index
      int b = row >> 10, t = row & 1023;
      if (region == 0) {
        int ty = x_type[b * TP1 + t];
        #pragma unroll
        for (int n = 0; n < 4; n++) {
          int cloc = (int)bn + wn * 64 + n * 16 + (lane & 15);       // 0..511
          int h = cloc >> 6, hd = cloc & 63;
          float v = acc[i][n][jj] + type_emb[(size_t)ty * 1024 + cloc];
          float vp = __shfl_xor(v, 1);
          if (hd < 32) {
            int p = hd >> 1;
            float c = rqc[row * 16 + p], s = rqs[row * 16 + p];
            v = (hd & 1) ? (v * c + vp * s) : (v * c - vp * s);
          }
          qT[((size_t)(b * 8 + h) * T_ + t) * 64 + hd] = f2b(v * QSCALE);
        }
      } else if (region == 1) {
        int ty = x_type[b * TP1 + t + 1];
        #pragma unroll
        for (int n = 0; n < 4; n++) {
          int cloc = (int)bn - 512 + wn * 64 + n * 16 + (lane & 15); // 0..511
          int h = cloc >> 6, hd = cloc & 63;
          float v = acc[i][n][jj] + type_emb[(size_t)ty * 1024 + 512 + cloc];
          float vp = __shfl_xor(v, 1);
          if (hd < 32) {
            int p = hd >> 1;
            float c = rkc[row * 16 + p], s = rks[row * 16 + p];
            v = (hd & 1) ? (v * c + vp * s) : (v * c - vp * s);
          }
          kT[((size_t)(b * 8 + h) * T_ + t) * 64 + hd] = f2b(v);
        }
      } else {
        #pragma unroll
        for (int n = 0; n < 4; n++) {
          int cloc = (int)bn - 1024 + wn * 64 + n * 16 + (lane & 15);
          int h = cloc >> 6, hd = cloc & 63;
          vT[((size_t)(b * 8 + h) * 64 + hd) * T_ + t] = f2b(acc[i][n][jj]);
        }
      }
    }
  }
}

// ---------------- FF1 GEMM with fused bias + SwiGLU epilogue -> bf16 ----------------
__global__ __launch_bounds__(256) void gemm_ff1(const u16* __restrict__ A,
    const u16* __restrict__ Bt, const float* __restrict__ b1,
    u16* __restrict__ outp) {
  __shared__ u16 lA[2][4096];
  __shared__ u16 lBa[2][4096];
  __shared__ u16 lBg[2][4096];
  const int K = 512;
  const int tid = threadIdx.x, lane = tid & 63, w = tid >> 6;
  const int wm = w >> 1, wn = w & 1;
  int swz = (blockIdx.x & 7) * 64 + (blockIdx.x >> 3);   // 512 blocks
  int byy = swz >> 3, bxx = swz & 7;
  const size_t bm = (size_t)byy * 128;
  const size_t bn = (size_t)bxx * 128;

  const int r0 = tid >> 2;
  const int cs = ((tid & 3) ^ ((r0 >> 1) & 3)) * 8;
  const u16* a0  = A + (bm + r0) * K + cs;
  const u16* a1  = A + (bm + 64 + r0) * K + cs;
  const u16* ba0 = Bt + (bn + r0) * K + cs;
  const u16* ba1 = Bt + (bn + 64 + r0) * K + cs;
  const u16* bg0 = Bt + (1024 + bn + r0) * K + cs;
  const u16* bg1 = Bt + (1024 + bn + 64 + r0) * K + cs;

  int aoff[4], boff[4];
  #pragma unroll
  for (int i = 0; i < 4; i++) {
    int ra = wm * 64 + i * 16 + (lane & 15);
    aoff[i] = ra * 64 + (((lane >> 4) ^ ((ra >> 1) & 3)) * 16);
    int rb = wn * 64 + i * 16 + (lane & 15);
    boff[i] = rb * 64 + (((lane >> 4) ^ ((rb >> 1) & 3)) * 16);
  }

  auto stage = [&](int k0, int buf) {
    char* ad  = (char*)lA  + buf * 8192 + w * 1024;
    char* bad = (char*)lBa + buf * 8192 + w * 1024;
    char* bgd = (char*)lBg + buf * 8192 + w * 1024;
    gld16(a0 + k0, ad);
    gld16(a1 + k0, ad + 4096);
    gld16(ba0 + k0, bad);
    gld16(ba1 + k0, bad + 4096);
    gld16(bg0 + k0, bgd);
    gld16(bg1 + k0, bgd + 4096);
  };

  f32x4 aca[4][4] = {}, acg[4][4] = {};
  stage(0, 0);
  __syncthreads();
  int cur = 0;
  for (int k0 = 0; k0 < K; k0 += 32) {
    if (k0 + 32 < K) stage(k0 + 32, cur ^ 1);
    const char* lAc  = (const char*)lA  + cur * 8192;
    const char* lBac = (const char*)lBa + cur * 8192;
    const char* lBgc = (const char*)lBg + cur * 8192;
    bf16x8 af[4], bfa[4], bfg[4];
    #pragma unroll
    for (int i = 0; i < 4; i++) af[i]  = *(const bf16x8*)(lAc  + aoff[i]);
    #pragma unroll
    for (int n = 0; n < 4; n++) bfa[n] = *(const bf16x8*)(lBac + boff[n]);
    #pragma unroll
    for (int n = 0; n < 4; n++) bfg[n] = *(const bf16x8*)(lBgc + boff[n]);
    __builtin_amdgcn_s_setprio(1);
    #pragma unroll
    for (int i = 0; i < 4; i++) {
      #pragma unroll
      for (int n = 0; n < 4; n++) {
        aca[i][n] = mfma16(af[i], bfa[n], aca[i][n]);
        acg[i][n] = mfma16(af[i], bfg[n], acg[i][n]);
      }
    }
    __builtin_amdgcn_s_setprio(0);
    __syncthreads();
    cur ^= 1;
  }
  #pragma unroll
  for (int i = 0; i < 4; i++) {
    #pragma unroll
    for (int n = 0; n < 4; n++) {
      int col = (int)bn + wn * 64 + n * 16 + (lane & 15);
      float bav = b1[col], bgv = b1[1024 + col];
      #pragma unroll
      for (int jj = 0; jj < 4; jj++) {
        int row = (int)bm + wm * 64 + i * 16 + (lane >> 4) * 4 + jj;
        float av = aca[i][n][jj] + bav;
        float gv = acg[i][n][jj] + bgv;
        float sg = gv / (1.f + expf(-gv));
        outp[(size_t)row * 1024 + col] = f2b(sg * av);
      }
    }
  }
}

// ---------------- FF2 GEMM, 512 thr / 8 waves ----------------
__global__ __launch_bounds__(512) void gemm_ff2(const u16* __restrict__ A,
    const u16* __restrict__ Bt, const float* __restrict__ bias,
    float* __restrict__ C) {
  __shared__ u16 lA[2][4096];
  __shared__ u16 lB[2][4096];
  const int K = 1024, N = 512;
  const int tid = threadIdx.x, lane = tid & 63, w = tid >> 6;   // w 0..7
  const int wm = w >> 2, wn = w & 3;                            // 2x4 waves: 64x32 each
  int swz = (blockIdx.x & 7) * 32 + (blockIdx.x >> 3);          // 256 blocks
  int byy = swz >> 2, bxx = swz & 3;
  const size_t bm = (size_t)byy * 128;
  const size_t bn = (size_t)bxx * 128;

  const int r0 = tid >> 2;                                      // 0..127
  const int cs = ((tid & 3) ^ ((r0 >> 1) & 3)) * 8;
  const u16* a0 = A + (bm + r0) * K + cs;
  const u16* b0 = Bt + (bn + r0) * K + cs;

  int aoff[4], boff[2];
  #pragma unroll
  for (int i = 0; i < 4; i++) {
    int ra = wm * 64 + i * 16 + (lane & 15);
    aoff[i] = ra * 64 + (((lane >> 4) ^ ((ra >> 1) & 3)) * 16);
  }
  #pragma unroll
  for (int n = 0; n < 2; n++) {
    int rb = wn * 32 + n * 16 + (lane & 15);
    boff[n] = rb * 64 + (((lane >> 4) ^ ((rb >> 1) & 3)) * 16);
  }

  auto stage = [&](int k0, int buf) {      // 512 thr: one call covers full 8KB tile
    gld16(a0 + k0, (char*)lA + buf * 8192 + w * 1024);
    gld16(b0 + k0, (char*)lB + buf * 8192 + w * 1024);
  };

  f32x4 acc[4][2] = {};
  stage(0, 0);
  __syncthreads();
  int cur = 0;
  for (int k0 = 0; k0 < K; k0 += 32) {
    if (k0 + 32 < K) stage(k0 + 32, cur ^ 1);
    const char* lAc = (const char*)lA + cur * 8192;
    const char* lBc = (const char*)lB + cur * 8192;
    bf16x8 af[4], bf[2];
    #pragma unroll
    for (int i = 0; i < 4; i++) af[i] = *(const bf16x8*)(lAc + aoff[i]);
    #pragma unroll
    for (int n = 0; n < 2; n++) bf[n] = *(const bf16x8*)(lBc + boff[n]);
    __builtin_amdgcn_s_setprio(1);
    #pragma unroll
    for (int i = 0; i < 4; i++)
      #pragma unroll
      for (int n = 0; n < 2; n++)
        acc[i][n] = mfma16(af[i], bf[n], acc[i][n]);
    __builtin_amdgcn_s_setprio(0);
    __syncthreads();
    cur ^= 1;
  }
  #pragma unroll
  for (int i = 0; i < 4; i++) {
    size_t mrow = bm + wm * 64 + i * 16 + (lane >> 4) * 4;
    #pragma unroll
    for (int n = 0; n < 2; n++) {
      size_t col = bn + wn * 32 + n * 16 + (lane & 15);
      float bv = bias[col];
      #pragma unroll
      for (int jj = 0; jj < 4; jj++) {
        size_t idx = (mrow + jj) * (size_t)N + col;
        C[idx] = acc[i][n][jj] + bv + C[idx];   // in-place residual
      }
    }
  }
}

// ---------------- causal flash attention + residual: out = x_value + attn ----------------
// Swapped-operand S^T = mfma(K,Q): each lane owns one q-row's 16 k-values.
// Softmax fully in-register (2 shfl per reduce); P packed via v_cvt_pk_bf16_f32
// directly into the PV B-frag (zero shuffles; V A-frag reads the matching
// permuted k-order via 2x ds_read_b64, bank-balanced under the chunk-XOR swizzle).
__global__ __launch_bounds__(256) void attn_kernel(const u16* __restrict__ qT,
    const u16* __restrict__ kT, const u16* __restrict__ vT,
    const float* __restrict__ xv, float* __restrict__ X) {
  int swz = (blockIdx.x & 7) * 128 + (blockIdx.x >> 3);   // 1024 blocks, XCD-grouped by bh
  const int bh = swz >> 4;
  const int qb = 15 - (swz & 15);          // LPT within each XCD's stream
  const int b = bh >> 3, h = bh & 7;
  const int tid = threadIdx.x, lane = tid & 63, w = tid >> 6;
  const int q = lane & 15, g = lane >> 4;
  __shared__ u16 lK[2][4096];
  __shared__ u16 lV[2][4096];

  bf16x8 qf[2];
  {
    int row = qb * 64 + w * 16 + q;
    const u16* qp = qT + ((size_t)bh * T_ + row) * 64 + g * 8;
    qf[0] = *(const bf16x8*)qp;
    qf[1] = *(const bf16x8*)(qp + 32);
  }
  f32x4 acc[4] = {};
  float mr = -1e30f, lr = 0.f;

  const int sr = tid >> 3;
  const int scs = ((tid & 7) ^ (sr & 7)) * 8;
  const u16* kb0 = kT + ((size_t)bh * T_ + sr) * 64 + scs;
  const u16* kb1 = kT + ((size_t)bh * T_ + 32 + sr) * 64 + scs;
  const u16* vb0 = vT + ((size_t)bh * 64 + sr) * T_ + scs;
  const u16* vb1 = vT + ((size_t)bh * 64 + 32 + sr) * T_ + scs;

  auto stage = [&](int j, int buf) {
    char* kd = (char*)lK + buf * 8192 + w * 1024;
    char* vd = (char*)lV + buf * 8192 + w * 1024;
    gld16(kb0 + (size_t)j * 4096, kd);
    gld16(kb1 + (size_t)j * 4096, kd + 4096);
    gld16(vb0 + j * 64, vd);
    gld16(vb1 + j * 64, vd + 4096);
  };

  stage(0, 0);
  __syncthreads();
  int cur = 0;
  for (int j = 0; j <= qb; j++) {
    if (j < qb) stage(j + 1, cur ^ 1);     // prefetch next tile under compute
    const char* lKc = (const char*)lK + cur * 8192;
    const char* lVc = (const char*)lV + cur * 8192;

    // QK^T swapped: s[n][i] = S[k = n*16+g*4+i][q]
    f32x4 s[4] = {};
    __builtin_amdgcn_s_setprio(1);
    #pragma unroll
    for (int ka = 0; ka < 2; ka++) {
      #pragma unroll
      for (int n = 0; n < 4; n++) {
        bf16x8 kb = *(const bf16x8*)(lKc + (n * 16 + q) * 128 +
                                     (((ka * 4 + g) ^ (q & 7)) * 16));
        s[n] = mfma16(kb, qf[ka], s[n]);
      }
    }
    __builtin_amdgcn_s_setprio(0);
    if (j == qb) {                          // causal mask on diagonal block
      int qloc = w * 16 + q;
      #pragma unroll
      for (int n = 0; n < 4; n++)
        #pragma unroll
        for (int i = 0; i < 4; i++)
          if (n * 16 + g * 4 + i > qloc) s[n][i] = -1e30f;
    }
    // in-register softmax: one q-row per lane
    float mt = fmaxf(fmaxf(fmaxf(s[0][0], s[0][1]), fmaxf(s[0][2], s[0][3])),
                     fmaxf(fmaxf(s[1][0], s[1][1]), fmaxf(s[1][2], s[1][3])));
    mt = fmaxf(mt, fmaxf(fmaxf(fmaxf(s[2][0], s[2][1]), fmaxf(s[2][2], s[2][3])),
                         fmaxf(fmaxf(s[3][0], s[3][1]), fmaxf(s[3][2], s[3][3]))));
    mt = fmaxf(mt, __shfl_xor(mt, 16));
    mt = fmaxf(mt, __shfl_xor(mt, 32));
    if (__any(mt > mr + 8.f)) {             // defer-max: skip rescale when growth < 2^8
      float mnew = fmaxf(mr, mt);
      float sc = exp2f(mr - mnew);
      mr = mnew;
      lr *= sc;
      #pragma unroll
      for (int t = 0; t < 4; t++) acc[t] *= sc;
    }
    float p[4][4];
    float ps = 0.f;
    #pragma unroll
    for (int n = 0; n < 4; n++)
      #pragma unroll
      for (int i = 0; i < 4; i++) { p[n][i] = exp2f(s[n][i] - mr); ps += p[n][i]; }
    ps += __shfl_xor(ps, 16);
    ps += __shfl_xor(ps, 32);
    lr += ps;
    // pack P into PV B-frags (lane-local, no shuffles)
    U8 pa[2];
    #pragma unroll
    for (int kt = 0; kt < 2; kt++) {
      pa[kt].u[0] = cvtpk(p[2 * kt][0], p[2 * kt][1]);
      pa[kt].u[1] = cvtpk(p[2 * kt][2], p[2 * kt][3]);
      pa[kt].u[2] = cvtpk(p[2 * kt + 1][0], p[2 * kt + 1][1]);
      pa[kt].u[3] = cvtpk(p[2 * kt + 1][2], p[2 * kt + 1][3]);
    }
    // PV: O^T[d][q] += V^T[d][k'] * P^T[k'][q], k'(g,e) = kt*32+(e>>2)*16+g*4+(e&3)
    __builtin_amdgcn_s_setprio(1);
    #pragma unroll
    for (int t = 0; t < 4; t++) {
      const char* vr = lVc + (t * 16 + q) * 128 + (g & 1) * 8;
      #pragma unroll
      for (int kt = 0; kt < 2; kt++) {
        u32x2 lo = *(const u32x2*)(vr + (((kt * 4 + (g >> 1)) ^ (q & 7)) * 16));
        u32x2 hi = *(const u32x2*)(vr + (((kt * 4 + 2 + (g >> 1)) ^ (q & 7)) * 16));
        U8 af;
        af.u[0] = lo[0]; af.u[1] = lo[1]; af.u[2] = hi[0]; af.u[3] = hi[1];
        acc[t] = mfma16(af.v, pa[kt].v, acc[t]);
      }
    }
    __builtin_amdgcn_s_setprio(0);
    __syncthreads();                        // drains prefetch; publishes buf cur^1
    cur ^= 1;
  }
  // epilogue: lane owns q-row (qb*64+w*16+q), cols d = t*16+g*4+{0..3} -> f32x4
  {
    int qrow = qb * 64 + w * 16 + q;
    float inv = 1.f / lr;
    size_t base = ((size_t)b * T_ + qrow) * D_ + h * 64 + g * 4;
    #pragma unroll
    for (int t = 0; t < 4; t++) {
      f32x4 r = *(const f32x4*)(xv + base + t * 16);
      f32x4 o;
      #pragma unroll
      for (int i = 0; i < 4; i++) o[i] = r[i] + acc[t][i] * inv;
      *(f32x4*)(X + base + t * 16) = o;
    }
  }
}

// ------------------------------- launch -------------------------------
extern "C" void kernel_launch(void* const* d_in, const int* in_sizes, int n_in,
                              void* d_out, int out_size, void* d_ws, size_t ws_size,
                              hipStream_t stream) {
  const int*   x_type   = (const int*)d_in[0];
  const float* x_value  = (const float*)d_in[1];
  const float* seq      = (const float*)d_in[2];
  const float* W_attn   = (const float*)d_in[3];
  const float* type_emb = (const float*)d_in[4];
  const float* ln1_g    = (const float*)d_in[5];
  const float* ln1_b    = (const float*)d_in[6];
  const float* ln2_g    = (const float*)d_in[7];
  const float* ln2_b    = (const float*)d_in[8];
  const float* W1       = (const float*)d_in[9];
  const float* b1       = (const float*)d_in[10];
  const float* W2       = (const float*)d_in[11];
  const float* b2       = (const float*)d_in[12];
  float* out = (float*)d_out;
  char* ws = (char*)d_ws;

  // workspace layout — total ~38.5 MiB
  u16*   WtA  = (u16*)(ws + 0);             // 1536x512 bf16  1.5 MiB
  u16*   W1t  = (u16*)(ws + 1572864);       // 2048x512 bf16  2 MiB
  u16*   W2t  = (u16*)(ws + 3670016);       // 512x1024 bf16  1 MiB
  float* rqc  = (float*)(ws + 4718592);     // 4 rope tables, 512 KiB each
  float* rqs  = (float*)(ws + 5242880);
  float* rkc  = (float*)(ws + 5767168);
  float* rks  = (float*)(ws + 6291456);
  u16*   hbuf = (u16*)(ws + 6815744);       // 8192x512 bf16 (h, then h2)  8 MiB
  u16*   qTb  = (u16*)(ws + 15204352);      // (B,H,T,64) bf16  8 MiB
  u16*   kTb  = (u16*)(ws + 23592960);      // 8 MiB
  u16*   vTb  = (u16*)(ws + 31981568);      // (B,H,64,T) bf16  8 MiB
  u16*   ff1a = (u16*)(ws + 15204352);      // 8192x1024 bf16 16 MiB, aliases qT+kT (dead post-attn)

  transpose_cast<<<(1536 * 512 + 255) / 256, 256, 0, stream>>>(W_attn, WtA, 512, 1536);
  transpose_cast<<<(2048 * 512 + 255) / 256, 256, 0, stream>>>(W1, W1t, 512, 2048);
  transpose_cast<<<(512 * 1024 + 255) / 256, 256, 0, stream>>>(W2, W2t, 1024, 512);
  rope_tables<<<(B_ * T_ * 16) / 256, 256, 0, stream>>>(seq, rqc, rqs, rkc, rks);
  ln_kernel<<<B_ * T_ / 4, 256, 0, stream>>>(x_value, ln1_g, ln1_b, hbuf);
  gemm_qkv<<<768, 256, 0, stream>>>(hbuf, WtA, x_type, type_emb,
                                    rqc, rqs, rkc, rks, qTb, kTb, vTb);
  attn_kernel<<<1024, 256, 0, stream>>>(qTb, kTb, vTb, x_value, out);
  ln_kernel<<<B_ * T_ / 4, 256, 0, stream>>>(out, ln2_g, ln2_b, hbuf);
  gemm_ff1<<<512, 256, 0, stream>>>(hbuf, W1t, b1, ff1a);
  gemm_ff2<<<256, 512, 0, stream>>>(ff1a, W2t, b2, out);
}

// Round 5
// 153.222 us; speedup vs baseline: 1.5459x; 1.1590x over previous
//
#include <hip/hip_runtime.h>
#include <stdint.h>
#include <math.h>

typedef unsigned short u16;
typedef unsigned int u32;
typedef __attribute__((ext_vector_type(8))) short bf16x8;   // 8 bf16 (4 VGPRs) MFMA A/B frag
typedef __attribute__((ext_vector_type(4))) float f32x4;
typedef __attribute__((ext_vector_type(2))) float f32x2;
typedef __attribute__((ext_vector_type(2))) u16 u16x2;
typedef __attribute__((ext_vector_type(8))) u16 u16x8;
typedef __attribute__((ext_vector_type(2))) u32 u32x2;

#define B_ 8
#define T_ 1024
#define D_ 512
#define H_ 8
#define TP1 1025
// q scale: 1/sqrt(64) * log2(e)  (softmax runs in exp2 domain)
#define QSCALE 0.1803368801111204f

__device__ __forceinline__ u16 f2b(float f) {           // f32 -> bf16 RNE
  union { float f; u32 u; } v; v.f = f;
  return (u16)((v.u + 0x7fffu + ((v.u >> 16) & 1u)) >> 16);
}
__device__ __forceinline__ void gld16(const void* g, void* l) {
  // async global->LDS, 16B/lane; LDS dest = wave-uniform base + lane*16
  __builtin_amdgcn_global_load_lds((const __attribute__((address_space(1))) u32*)g,
                                   (__attribute__((address_space(3))) u32*)l, 16, 0, 0);
}
__device__ __forceinline__ f32x4 mfma16(bf16x8 a, bf16x8 b, f32x4 c) {
  return __builtin_amdgcn_mfma_f32_16x16x32_bf16(a, b, c, 0, 0, 0);
}
__device__ __forceinline__ u32 cvtpk(float lo, float hi) {   // 2xf32 -> packed bf16x2 (RNE)
  u32 r;
  asm("v_cvt_pk_bf16_f32 %0, %1, %2" : "=v"(r) : "v"(lo), "v"(hi));
  return r;
}
union U8 { u32 u[4]; bf16x8 v; };

// ---------------- fused prep: 3 weight transposes (W1 interleaved) + rope tables ----------------
// W1i[r][k] = W1[k][src(r)], src(r) = ((r>>4)&1)*1024 + ((r>>5)<<4) + (r&15):
// 16-col blocks of a/gate alternate so FF1 is a standard 2-operand GEMM.
__global__ __launch_bounds__(256) void prep_kernel(const float* __restrict__ W_attn,
    const float* __restrict__ W1, const float* __restrict__ W2,
    const float* __restrict__ seq,
    u16* __restrict__ WtA, u16* __restrict__ W1i, u16* __restrict__ W2t,
    float* __restrict__ cq, float* __restrict__ sq_,
    float* __restrict__ ck, float* __restrict__ sk) {
  int bid = blockIdx.x, tid = threadIdx.x;
  if (bid < 3072) {                  // WtA: 1536x512
    int i = bid * 256 + tid;
    int n = i >> 9, k = i & 511;
    WtA[i] = f2b(W_attn[(size_t)k * 1536 + n]);
  } else if (bid < 7168) {           // W1i interleaved: 2048x512
    int i = (bid - 3072) * 256 + tid;
    int r = i >> 9, k = i & 511;
    int src = ((r >> 4) & 1) * 1024 + ((r >> 5) << 4) + (r & 15);
    W1i[i] = f2b(W1[(size_t)k * 2048 + src]);
  } else if (bid < 9216) {           // W2t: 512x1024
    int i = (bid - 7168) * 256 + tid;
    int n = i >> 10, k = i & 1023;
    W2t[i] = f2b(W2[(size_t)k * 512 + n]);
  } else {                            // rope tables: B*T*16
    int i = (bid - 9216) * 256 + tid;
    int p = i & 15, bt = i >> 4, b = bt >> 10, t = bt & 1023;
    float inv = expf(-(float)p * 0.5756462732485115f);   // 10000^(-p/16)
    float aq = seq[b * TP1 + t] * inv;
    float ak = seq[b * TP1 + t + 1] * inv;
    cq[i] = cosf(aq); sq_[i] = sinf(aq);
    ck[i] = cosf(ak); sk[i] = sinf(ak);
  }
}

// ---------------- LayerNorm: one WAVE per row, no LDS, no barriers ----------------
__global__ __launch_bounds__(256) void ln_kernel(const float* __restrict__ x,
    const float* __restrict__ g, const float* __restrict__ bta, u16* __restrict__ out) {
  int row = blockIdx.x * 4 + (threadIdx.x >> 6);    // 8192 rows, 4 rows/block
  int lane = threadIdx.x & 63;
  const float* xr = x + (size_t)row * D_ + lane * 8;
  f32x4 v0 = *(const f32x4*)xr;
  f32x4 v1 = *(const f32x4*)(xr + 4);
  float s = 0.f, sq = 0.f;
  #pragma unroll
  for (int j = 0; j < 4; j++) { s += v0[j] + v1[j]; sq += v0[j] * v0[j] + v1[j] * v1[j]; }
  #pragma unroll
  for (int m = 1; m < 64; m <<= 1) { s += __shfl_xor(s, m); sq += __shfl_xor(sq, m); }
  float mean = s * (1.f / D_);
  float var = sq * (1.f / D_) - mean * mean;
  float rstd = rsqrtf(var + 1e-5f);
  f32x4 g0 = *(const f32x4*)(g + lane * 8);
  f32x4 g1 = *(const f32x4*)(g + lane * 8 + 4);
  f32x4 b0 = *(const f32x4*)(bta + lane * 8);
  f32x4 b1 = *(const f32x4*)(bta + lane * 8 + 4);
  u16x8 o;
  #pragma unroll
  for (int j = 0; j < 4; j++) {
    o[j]     = f2b((v0[j] - mean) * rstd * g0[j] + b0[j]);
    o[4 + j] = f2b((v1[j] - mean) * rstd * g1[j] + b1[j]);
  }
  *(u16x8*)(out + (size_t)row * D_ + lane * 8) = o;
}

// ============ GEMM tiles: 128x128, BK=32, double-buffered, XCD-remapped 1-D grid ============
// staging swizzle: stored[row][p] = global chunk p ^ s(row), s(row)=(row>>1)&3

// ---------------- QKV GEMM with fused type-emb + RoPE + scale + head-layout epilogue ----------------
__global__ __launch_bounds__(256) void gemm_qkv(const u16* __restrict__ A,
    const u16* __restrict__ Bt,
    const int* __restrict__ x_type, const float* __restrict__ type_emb,
    const float* __restrict__ rqc, const float* __restrict__ rqs,
    const float* __restrict__ rkc, const float* __restrict__ rks,
    u16* __restrict__ qT, u16* __restrict__ kT, u16* __restrict__ vT) {
  __shared__ u16 lA[2][4096];
  __shared__ u16 lB[2][4096];
  const int K = 512;
  const int tid = threadIdx.x, lane = tid & 63, w = tid >> 6;
  const int wm = w >> 1, wn = w & 1;
  // XCD remap: 768 blocks -> each XCD gets 8 contiguous row-panels (A reuse in its L2)
  int swz = (blockIdx.x & 7) * 96 + (blockIdx.x >> 3);
  int byy = swz / 12, bxx = swz - byy * 12;
  const size_t bm = (size_t)byy * 128;
  const size_t bn = (size_t)bxx * 128;

  const int r0 = tid >> 2;
  const int cs = ((tid & 3) ^ ((r0 >> 1) & 3)) * 8;
  const u16* a0 = A + (bm + r0) * K + cs;
  const u16* a1 = A + (bm + 64 + r0) * K + cs;
  const u16* b0 = Bt + (bn + r0) * K + cs;
  const u16* b1p = Bt + (bn + 64 + r0) * K + cs;

  int aoff[4], boff[4];
  #pragma unroll
  for (int i = 0; i < 4; i++) {
    int ra = wm * 64 + i * 16 + (lane & 15);
    aoff[i] = ra * 64 + (((lane >> 4) ^ ((ra >> 1) & 3)) * 16);
    int rb = wn * 64 + i * 16 + (lane & 15);
    boff[i] = rb * 64 + (((lane >> 4) ^ ((rb >> 1) & 3)) * 16);
  }

  auto stage = [&](int k0, int buf) {
    char* ad = (char*)lA + buf * 8192 + w * 1024;
    char* bd = (char*)lB + buf * 8192 + w * 1024;
    gld16(a0 + k0, ad);
    gld16(a1 + k0, ad + 4096);
    gld16(b0 + k0, bd);
    gld16(b1p + k0, bd + 4096);
  };

  f32x4 acc[4][4] = {};
  stage(0, 0);
  __syncthreads();
  int cur = 0;
  for (int k0 = 0; k0 < K; k0 += 32) {
    if (k0 + 32 < K) stage(k0 + 32, cur ^ 1);     // prefetch overlaps compute below
    const char* lAc = (const char*)lA + cur * 8192;
    const char* lBc = (const char*)lB + cur * 8192;
    bf16x8 af[4], bf[4];
    #pragma unroll
    for (int i = 0; i < 4; i++) af[i] = *(const bf16x8*)(lAc + aoff[i]);
    #pragma unroll
    for (int n = 0; n < 4; n++) bf[n] = *(const bf16x8*)(lBc + boff[n]);
    __builtin_amdgcn_s_setprio(1);
    #pragma unroll
    for (int i = 0; i < 4; i++)
      #pragma unroll
      for (int n = 0; n < 4; n++)
        acc[i][n] = mfma16(af[i], bf[n], acc[i][n]);
    __builtin_amdgcn_s_setprio(0);
    __syncthreads();
    cur ^= 1;
  }

  // fused epilogue. block-uniform region: 0=q (cols 0..511), 1=k, 2=v
  const int region = (int)(bn >> 9);
  #pragma unroll
  for (int i = 0; i < 4; i++) {
    #pragma unroll
    for (int jj = 0; jj < 4; jj++) {
      int row = (int)bm + wm * 64 + i * 16 + (lane >> 4) * 4 + jj;   // bt index
      int b = row >> 10, t = row & 1023;
      if (region == 0) {
        int ty = x_type[b * TP1 + t];
        #pragma unroll
        for (int n = 0; n < 4; n++) {
          int cloc = (int)bn + wn * 64 + n * 16 + (lane & 15);       // 0..511
          int h = cloc >> 6, hd = cloc & 63;
          float v = acc[i][n][jj] + type_emb[(size_t)ty * 1024 + cloc];
          float vp = __shfl_xor(v, 1);
          if (hd < 32) {
            int p = hd >> 1;
            float c = rqc[row * 16 + p], s = rqs[row * 16 + p];
            v = (hd & 1) ? (v * c + vp * s) : (v * c - vp * s);
          }
          qT[((size_t)(b * 8 + h) * T_ + t) * 64 + hd] = f2b(v * QSCALE);
        }
      } else if (region == 1) {
        int ty = x_type[b * TP1 + t + 1];
        #pragma unroll
        for (int n = 0; n < 4; n++) {
          int cloc = (int)bn - 512 + wn * 64 + n * 16 + (lane & 15); // 0..511
          int h = cloc >> 6, hd = cloc & 63;
          float v = acc[i][n][jj] + type_emb[(size_t)ty * 1024 + 512 + cloc];
          float vp = __shfl_xor(v, 1);
          if (hd < 32) {
            int p = hd >> 1;
            float c = rkc[row * 16 + p], s = rks[row * 16 + p];
            v = (hd & 1) ? (v * c + vp * s) : (v * c - vp * s);
          }
          kT[((size_t)(b * 8 + h) * T_ + t) * 64 + hd] = f2b(v);
        }
      } else {
        #pragma unroll
        for (int n = 0; n < 4; n++) {
          int cloc = (int)bn - 1024 + wn * 64 + n * 16 + (lane & 15);
          int h = cloc >> 6, hd = cloc & 63;
          vT[((size_t)(b * 8 + h) * 64 + hd) * T_ + t] = f2b(acc[i][n][jj]);
        }
      }
    }
  }
}

// ---------------- FF1 GEMM on interleaved W1i: standard 2-operand + in-lane SwiGLU ----------------
// n-even subtile = a-cols, n-odd subtile = gate-cols for the SAME real cols.
__global__ __launch_bounds__(256) void gemm_ff1(const u16* __restrict__ A,
    const u16* __restrict__ Bt, const float* __restrict__ b1,
    u16* __restrict__ outp) {
  __shared__ u16 lA[2][4096];
  __shared__ u16 lB[2][4096];
  const int K = 512;
  const int tid = threadIdx.x, lane = tid & 63, w = tid >> 6;
  const int wm = w >> 1, wn = w & 1;
  int swz = (blockIdx.x & 7) * 128 + (blockIdx.x >> 3);   // 1024 blocks
  int byy = swz >> 4, bxx = swz & 15;                     // per XCD: 8 row-panels x all cols
  const size_t bm = (size_t)byy * 128;
  const size_t bn = (size_t)bxx * 128;

  const int r0 = tid >> 2;
  const int cs = ((tid & 3) ^ ((r0 >> 1) & 3)) * 8;
  const u16* a0 = A + (bm + r0) * K + cs;
  const u16* a1 = A + (bm + 64 + r0) * K + cs;
  const u16* b0 = Bt + (bn + r0) * K + cs;
  const u16* b1p = Bt + (bn + 64 + r0) * K + cs;

  int aoff[4], boff[4];
  #pragma unroll
  for (int i = 0; i < 4; i++) {
    int ra = wm * 64 + i * 16 + (lane & 15);
    aoff[i] = ra * 64 + (((lane >> 4) ^ ((ra >> 1) & 3)) * 16);
    int rb = wn * 64 + i * 16 + (lane & 15);
    boff[i] = rb * 64 + (((lane >> 4) ^ ((rb >> 1) & 3)) * 16);
  }

  auto stage = [&](int k0, int buf) {
    char* ad = (char*)lA + buf * 8192 + w * 1024;
    char* bd = (char*)lB + buf * 8192 + w * 1024;
    gld16(a0 + k0, ad);
    gld16(a1 + k0, ad + 4096);
    gld16(b0 + k0, bd);
    gld16(b1p + k0, bd + 4096);
  };

  f32x4 acc[4][4] = {};
  stage(0, 0);
  __syncthreads();
  int cur = 0;
  for (int k0 = 0; k0 < K; k0 += 32) {
    if (k0 + 32 < K) stage(k0 + 32, cur ^ 1);
    const char* lAc = (const char*)lA + cur * 8192;
    const char* lBc = (const char*)lB + cur * 8192;
    bf16x8 af[4], bf[4];
    #pragma unroll
    for (int i = 0; i < 4; i++) af[i] = *(const bf16x8*)(lAc + aoff[i]);
    #pragma unroll
    for (int n = 0; n < 4; n++) bf[n] = *(const bf16x8*)(lBc + boff[n]);
    __builtin_amdgcn_s_setprio(1);
    #pragma unroll
    for (int i = 0; i < 4; i++)
      #pragma unroll
      for (int n = 0; n < 4; n++)
        acc[i][n] = mfma16(af[i], bf[n], acc[i][n]);
    __builtin_amdgcn_s_setprio(0);
    __syncthreads();
    cur ^= 1;
  }
  // epilogue: real col c = bn/2 + wn*32 + np*16 + (lane&15); a = acc[i][2np], g = acc[i][2np+1]
  #pragma unroll
  for (int np = 0; np < 2; np++) {
    int c = ((int)bn >> 1) + wn * 32 + np * 16 + (lane & 15);
    float bav = b1[c], bgv = b1[1024 + c];
    #pragma unroll
    for (int i = 0; i < 4; i++) {
      #pragma unroll
      for (int jj = 0; jj < 4; jj++) {
        int row = (int)bm + wm * 64 + i * 16 + (lane >> 4) * 4 + jj;
        float av = acc[i][2 * np][jj] + bav;
        float gv = acc[i][2 * np + 1][jj] + bgv;
        float sg = gv / (1.f + expf(-gv));
        outp[(size_t)row * 1024 + c] = f2b(sg * av);
      }
    }
  }
}

// ---------------- FF2 GEMM, 512 thr / 8 waves ----------------
__global__ __launch_bounds__(512) void gemm_ff2(const u16* __restrict__ A,
    const u16* __restrict__ Bt, const float* __restrict__ bias,
    float* __restrict__ C) {
  __shared__ u16 lA[2][4096];
  __shared__ u16 lB[2][4096];
  const int K = 1024, N = 512;
  const int tid = threadIdx.x, lane = tid & 63, w = tid >> 6;   // w 0..7
  const int wm = w >> 2, wn = w & 3;                            // 2x4 waves: 64x32 each
  int swz = (blockIdx.x & 7) * 32 + (blockIdx.x >> 3);          // 256 blocks
  int byy = swz >> 2, bxx = swz & 3;
  const size_t bm = (size_t)byy * 128;
  const size_t bn = (size_t)bxx * 128;

  const int r0 = tid >> 2;                                      // 0..127
  const int cs = ((tid & 3) ^ ((r0 >> 1) & 3)) * 8;
  const u16* a0 = A + (bm + r0) * K + cs;
  const u16* b0 = Bt + (bn + r0) * K + cs;

  int aoff[4], boff[2];
  #pragma unroll
  for (int i = 0; i < 4; i++) {
    int ra = wm * 64 + i * 16 + (lane & 15);
    aoff[i] = ra * 64 + (((lane >> 4) ^ ((ra >> 1) & 3)) * 16);
  }
  #pragma unroll
  for (int n = 0; n < 2; n++) {
    int rb = wn * 32 + n * 16 + (lane & 15);
    boff[n] = rb * 64 + (((lane >> 4) ^ ((rb >> 1) & 3)) * 16);
  }

  auto stage = [&](int k0, int buf) {      // 512 thr: one call covers full 8KB tile
    gld16(a0 + k0, (char*)lA + buf * 8192 + w * 1024);
    gld16(b0 + k0, (char*)lB + buf * 8192 + w * 1024);
  };

  f32x4 acc[4][2] = {};
  stage(0, 0);
  __syncthreads();
  int cur = 0;
  for (int k0 = 0; k0 < K; k0 += 32) {
    if (k0 + 32 < K) stage(k0 + 32, cur ^ 1);
    const char* lAc = (const char*)lA + cur * 8192;
    const char* lBc = (const char*)lB + cur * 8192;
    bf16x8 af[4], bf[2];
    #pragma unroll
    for (int i = 0; i < 4; i++) af[i] = *(const bf16x8*)(lAc + aoff[i]);
    #pragma unroll
    for (int n = 0; n < 2; n++) bf[n] = *(const bf16x8*)(lBc + boff[n]);
    __builtin_amdgcn_s_setprio(1);
    #pragma unroll
    for (int i = 0; i < 4; i++)
      #pragma unroll
      for (int n = 0; n < 2; n++)
        acc[i][n] = mfma16(af[i], bf[n], acc[i][n]);
    __builtin_amdgcn_s_setprio(0);
    __syncthreads();
    cur ^= 1;
  }
  #pragma unroll
  for (int i = 0; i < 4; i++) {
    size_t mrow = bm + wm * 64 + i * 16 + (lane >> 4) * 4;
    #pragma unroll
    for (int n = 0; n < 2; n++) {
      size_t col = bn + wn * 32 + n * 16 + (lane & 15);
      float bv = bias[col];
      #pragma unroll
      for (int jj = 0; jj < 4; jj++) {
        size_t idx = (mrow + jj) * (size_t)N + col;
        C[idx] = acc[i][n][jj] + bv + C[idx];   // in-place residual
      }
    }
  }
}

// ---------------- causal flash attention + residual: out = x_value + attn ----------------
// Swapped-operand S^T = mfma(K,Q): each lane owns one q-row's 16 k-values.
// Softmax fully in-register; P packed via v_cvt_pk_bf16_f32 directly into the
// PV B-frag (zero shuffles); V A-frag reads matching permuted k-order.
__global__ __launch_bounds__(256) void attn_kernel(const u16* __restrict__ qT,
    const u16* __restrict__ kT, const u16* __restrict__ vT,
    const float* __restrict__ xv, float* __restrict__ X) {
  int swz = (blockIdx.x & 7) * 128 + (blockIdx.x >> 3);   // 1024 blocks, XCD-grouped by bh
  const int bh = swz >> 4;
  const int qb = 15 - (swz & 15);          // LPT within each XCD's stream
  const int b = bh >> 3, h = bh & 7;
  const int tid = threadIdx.x, lane = tid & 63, w = tid >> 6;
  const int q = lane & 15, g = lane >> 4;
  __shared__ u16 lK[2][4096];
  __shared__ u16 lV[2][4096];

  bf16x8 qf[2];
  {
    int row = qb * 64 + w * 16 + q;
    const u16* qp = qT + ((size_t)bh * T_ + row) * 64 + g * 8;
    qf[0] = *(const bf16x8*)qp;
    qf[1] = *(const bf16x8*)(qp + 32);
  }
  f32x4 acc[4] = {};
  float mr = -1e30f, lr = 0.f;

  const int sr = tid >> 3;
  const int scs = ((tid & 7) ^ (sr & 7)) * 8;
  const u16* kb0 = kT + ((size_t)bh * T_ + sr) * 64 + scs;
  const u16* kb1 = kT + ((size_t)bh * T_ + 32 + sr) * 64 + scs;
  const u16* vb0 = vT + ((size_t)bh * 64 + sr) * T_ + scs;
  const u16* vb1 = vT + ((size_t)bh * 64 + 32 + sr) * T_ + scs;

  auto stage = [&](int j, int buf) {
    char* kd = (char*)lK + buf * 8192 + w * 1024;
    char* vd = (char*)lV + buf * 8192 + w * 1024;
    gld16(kb0 + (size_t)j * 4096, kd);
    gld16(kb1 + (size_t)j * 4096, kd + 4096);
    gld16(vb0 + j * 64, vd);
    gld16(vb1 + j * 64, vd + 4096);
  };

  stage(0, 0);
  __syncthreads();
  int cur = 0;
  for (int j = 0; j <= qb; j++) {
    if (j < qb) stage(j + 1, cur ^ 1);     // prefetch next tile under compute
    const char* lKc = (const char*)lK + cur * 8192;
    const char* lVc = (const char*)lV + cur * 8192;

    // QK^T swapped: s[n][i] = S[k = n*16+g*4+i][q]
    f32x4 s[4] = {};
    __builtin_amdgcn_s_setprio(1);
    #pragma unroll
    for (int ka = 0; ka < 2; ka++) {
      #pragma unroll
      for (int n = 0; n < 4; n++) {
        bf16x8 kb = *(const bf16x8*)(lKc + (n * 16 + q) * 128 +
                                     (((ka * 4 + g) ^ (q & 7)) * 16));
        s[n] = mfma16(kb, qf[ka], s[n]);
      }
    }
    __builtin_amdgcn_s_setprio(0);
    if (j == qb) {                          // causal mask on diagonal block
      int qloc = w * 16 + q;
      #pragma unroll
      for (int n = 0; n < 4; n++)
        #pragma unroll
        for (int i = 0; i < 4; i++)
          if (n * 16 + g * 4 + i > qloc) s[n][i] = -1e30f;
    }
    // in-register softmax: one q-row per lane
    float mt = fmaxf(fmaxf(fmaxf(s[0][0], s[0][1]), fmaxf(s[0][2], s[0][3])),
                     fmaxf(fmaxf(s[1][0], s[1][1]), fmaxf(s[1][2], s[1][3])));
    mt = fmaxf(mt, fmaxf(fmaxf(fmaxf(s[2][0], s[2][1]), fmaxf(s[2][2], s[2][3])),
                         fmaxf(fmaxf(s[3][0], s[3][1]), fmaxf(s[3][2], s[3][3]))));
    mt = fmaxf(mt, __shfl_xor(mt, 16));
    mt = fmaxf(mt, __shfl_xor(mt, 32));
    if (__any(mt > mr + 8.f)) {             // defer-max: skip rescale when growth < 2^8
      float mnew = fmaxf(mr, mt);
      float sc = exp2f(mr - mnew);
      mr = mnew;
      lr *= sc;
      #pragma unroll
      for (int t = 0; t < 4; t++) acc[t] *= sc;
    }
    float p[4][4];
    float ps = 0.f;
    #pragma unroll
    for (int n = 0; n < 4; n++)
      #pragma unroll
      for (int i = 0; i < 4; i++) { p[n][i] = exp2f(s[n][i] - mr); ps += p[n][i]; }
    ps += __shfl_xor(ps, 16);
    ps += __shfl_xor(ps, 32);
    lr += ps;
    // pack P into PV B-frags (lane-local, no shuffles)
    U8 pa[2];
    #pragma unroll
    for (int kt = 0; kt < 2; kt++) {
      pa[kt].u[0] = cvtpk(p[2 * kt][0], p[2 * kt][1]);
      pa[kt].u[1] = cvtpk(p[2 * kt][2], p[2 * kt][3]);
      pa[kt].u[2] = cvtpk(p[2 * kt + 1][0], p[2 * kt + 1][1]);
      pa[kt].u[3] = cvtpk(p[2 * kt + 1][2], p[2 * kt + 1][3]);
    }
    // PV: O^T[d][q] += V^T[d][k'] * P^T[k'][q], k'(g,e) = kt*32+(e>>2)*16+g*4+(e&3)
    __builtin_amdgcn_s_setprio(1);
    #pragma unroll
    for (int t = 0; t < 4; t++) {
      const char* vr = lVc + (t * 16 + q) * 128 + (g & 1) * 8;
      #pragma unroll
      for (int kt = 0; kt < 2; kt++) {
        u32x2 lo = *(const u32x2*)(vr + (((kt * 4 + (g >> 1)) ^ (q & 7)) * 16));
        u32x2 hi = *(const u32x2*)(vr + (((kt * 4 + 2 + (g >> 1)) ^ (q & 7)) * 16));
        U8 af;
        af.u[0] = lo[0]; af.u[1] = lo[1]; af.u[2] = hi[0]; af.u[3] = hi[1];
        acc[t] = mfma16(af.v, pa[kt].v, acc[t]);
      }
    }
    __builtin_amdgcn_s_setprio(0);
    __syncthreads();                        // drains prefetch; publishes buf cur^1
    cur ^= 1;
  }
  // epilogue: lane owns q-row (qb*64+w*16+q), cols d = t*16+g*4+{0..3} -> f32x4
  {
    int qrow = qb * 64 + w * 16 + q;
    float inv = 1.f / lr;
    size_t base = ((size_t)b * T_ + qrow) * D_ + h * 64 + g * 4;
    #pragma unroll
    for (int t = 0; t < 4; t++) {
      f32x4 r = *(const f32x4*)(xv + base + t * 16);
      f32x4 o;
      #pragma unroll
      for (int i = 0; i < 4; i++) o[i] = r[i] + acc[t][i] * inv;
      *(f32x4*)(X + base + t * 16) = o;
    }
  }
}

// ------------------------------- launch -------------------------------
extern "C" void kernel_launch(void* const* d_in, const int* in_sizes, int n_in,
                              void* d_out, int out_size, void* d_ws, size_t ws_size,
                              hipStream_t stream) {
  const int*   x_type   = (const int*)d_in[0];
  const float* x_value  = (const float*)d_in[1];
  const float* seq      = (const float*)d_in[2];
  const float* W_attn   = (const float*)d_in[3];
  const float* type_emb = (const float*)d_in[4];
  const float* ln1_g    = (const float*)d_in[5];
  const float* ln1_b    = (const float*)d_in[6];
  const float* ln2_g    = (const float*)d_in[7];
  const float* ln2_b    = (const float*)d_in[8];
  const float* W1       = (const float*)d_in[9];
  const float* b1       = (const float*)d_in[10];
  const float* W2       = (const float*)d_in[11];
  const float* b2       = (const float*)d_in[12];
  float* out = (float*)d_out;
  char* ws = (char*)d_ws;

  // workspace layout — total ~38.5 MiB
  u16*   WtA  = (u16*)(ws + 0);             // 1536x512 bf16  1.5 MiB
  u16*   W1i  = (u16*)(ws + 1572864);       // 2048x512 bf16 interleaved a/gate  2 MiB
  u16*   W2t  = (u16*)(ws + 3670016);       // 512x1024 bf16  1 MiB
  float* rqc  = (float*)(ws + 4718592);     // 4 rope tables, 512 KiB each
  float* rqs  = (float*)(ws + 5242880);
  float* rkc  = (float*)(ws + 5767168);
  float* rks  = (float*)(ws + 6291456);
  u16*   hbuf = (u16*)(ws + 6815744);       // 8192x512 bf16 (h, then h2)  8 MiB
  u16*   qTb  = (u16*)(ws + 15204352);      // (B,H,T,64) bf16  8 MiB
  u16*   kTb  = (u16*)(ws + 23592960);      // 8 MiB
  u16*   vTb  = (u16*)(ws + 31981568);      // (B,H,64,T) bf16  8 MiB
  u16*   ff1a = (u16*)(ws + 15204352);      // 8192x1024 bf16 16 MiB, aliases qT+kT (dead post-attn)

  prep_kernel<<<9728, 256, 0, stream>>>(W_attn, W1, W2, seq, WtA, W1i, W2t,
                                        rqc, rqs, rkc, rks);
  ln_kernel<<<B_ * T_ / 4, 256, 0, stream>>>(x_value, ln1_g, ln1_b, hbuf);
  gemm_qkv<<<768, 256, 0, stream>>>(hbuf, WtA, x_type, type_emb,
                                    rqc, rqs, rkc, rks, qTb, kTb, vTb);
  attn_kernel<<<1024, 256, 0, stream>>>(qTb, kTb, vTb, x_value, out);
  ln_kernel<<<B_ * T_ / 4, 256, 0, stream>>>(out, ln2_g, ln2_b, hbuf);
  gemm_ff1<<<1024, 256, 0, stream>>>(hbuf, W1i, b1, ff1a);
  gemm_ff2<<<256, 512, 0, stream>>>(ff1a, W2t, b2, out);
}

// Round 6
// 143.214 us; speedup vs baseline: 1.6539x; 1.0699x over previous
//
#include <hip/hip_runtime.h>
#include <stdint.h>
#include <math.h>

typedef unsigned short u16;
typedef unsigned int u32;
typedef __attribute__((ext_vector_type(8))) short bf16x8;   // 8 bf16 (4 VGPRs) MFMA A/B frag
typedef __attribute__((ext_vector_type(4))) float f32x4;
typedef __attribute__((ext_vector_type(2))) float f32x2;
typedef __attribute__((ext_vector_type(2))) u16 u16x2;
typedef __attribute__((ext_vector_type(8))) u16 u16x8;
typedef __attribute__((ext_vector_type(2))) u32 u32x2;

#define B_ 8
#define T_ 1024
#define D_ 512
#define H_ 8
#define TP1 1025
// q scale: 1/sqrt(64) * log2(e)  (softmax runs in exp2 domain)
#define QSCALE 0.1803368801111204f

__device__ __forceinline__ u16 f2b(float f) {           // f32 -> bf16 RNE
  union { float f; u32 u; } v; v.f = f;
  return (u16)((v.u + 0x7fffu + ((v.u >> 16) & 1u)) >> 16);
}
__device__ __forceinline__ void gld16(const void* g, void* l) {
  // async global->LDS, 16B/lane; LDS dest = wave-uniform base + lane*16
  __builtin_amdgcn_global_load_lds((const __attribute__((address_space(1))) u32*)g,
                                   (__attribute__((address_space(3))) u32*)l, 16, 0, 0);
}
__device__ __forceinline__ f32x4 mfma16(bf16x8 a, bf16x8 b, f32x4 c) {
  return __builtin_amdgcn_mfma_f32_16x16x32_bf16(a, b, c, 0, 0, 0);
}
__device__ __forceinline__ u32 cvtpk(float lo, float hi) {   // 2xf32 -> packed bf16x2 (RNE)
  u32 r;
  asm("v_cvt_pk_bf16_f32 %0, %1, %2" : "=v"(r) : "v"(lo), "v"(hi));
  return r;
}
union U8 { u32 u[4]; bf16x8 v; };

// ---------------- fused prep: tiled (coalesced) weight transposes + rope tables ----------------
// blocks 0..191    WtA  (dst 1536x512 from W_attn 512x1536)
// blocks 192..447  W1i  (dst 2048x512 from W1 512x2048, a/gate 16-col interleave)
// blocks 448..575  W2t  (dst 512x1024 from W2 1024x512)
// blocks 576..1087 rope tables
__global__ __launch_bounds__(256) void prep_kernel(const float* __restrict__ W_attn,
    const float* __restrict__ W1, const float* __restrict__ W2,
    const float* __restrict__ seq,
    u16* __restrict__ WtA, u16* __restrict__ W1i, u16* __restrict__ W2t,
    float* __restrict__ cq, float* __restrict__ sq_,
    float* __restrict__ ck, float* __restrict__ sk) {
  int bid = blockIdx.x, tid = threadIdx.x;
  if (bid >= 576) {                        // rope: B*T*16 elements
    int i = (bid - 576) * 256 + tid;
    int p = i & 15, bt = i >> 4, b = bt >> 10, t = bt & 1023;
    float inv = expf(-(float)p * 0.5756462732485115f);   // 10000^(-p/16)
    float aq = seq[b * TP1 + t] * inv;
    float ak = seq[b * TP1 + t + 1] * inv;
    cq[i] = cosf(aq); sq_[i] = sinf(aq);
    ck[i] = cosf(ak); sk[i] = sinf(ak);
    return;
  }
  __shared__ u16 lt[64][65];
  const float* src; u16* dst; int ld, Kd, k0, r0; bool ilv = false;
  if (bid < 192) {            // WtA: 8 k-tiles x 24 n-tiles
    src = W_attn; dst = WtA; ld = 1536; Kd = 512;
    k0 = (bid & 7) * 64; r0 = (bid >> 3) * 64;
  } else if (bid < 448) {     // W1i: 8 k-tiles x 32 r-tiles, interleaved
    int t = bid - 192;
    src = W1; dst = W1i; ld = 2048; Kd = 512; ilv = true;
    k0 = (t & 7) * 64; r0 = (t >> 3) * 64;
  } else {                    // W2t: 16 k-tiles x 8 n-tiles
    int t = bid - 448;
    src = W2; dst = W2t; ld = 512; Kd = 1024;
    k0 = (t & 15) * 64; r0 = (t >> 4) * 64;
  }
  int nl = tid & 63;
  // source column and destination-local row for this lane
  int scol, rloc;
  if (ilv) {
    if (nl < 32) { scol = (r0 >> 1) + nl;          rloc = ((nl >> 4) << 5) + (nl & 15); }
    else         { scol = 1024 + (r0 >> 1) + (nl - 32); rloc = (((nl - 32) >> 4) << 5) + 16 + (nl & 15); }
  } else { scol = r0 + nl; rloc = nl; }
  #pragma unroll
  for (int it = 0; it < 16; it++) {
    int kl = (tid >> 6) * 16 + it;
    lt[rloc][kl] = f2b(src[(size_t)(k0 + kl) * ld + scol]);
  }
  __syncthreads();
  #pragma unroll
  for (int it = 0; it < 16; it++) {
    int rl = (tid >> 6) * 16 + it;
    dst[(size_t)(r0 + rl) * Kd + k0 + nl] = lt[rl][nl];
  }
}

// ---------------- LayerNorm: one WAVE per row, no LDS, no barriers ----------------
__global__ __launch_bounds__(256) void ln_kernel(const float* __restrict__ x,
    const float* __restrict__ g, const float* __restrict__ bta, u16* __restrict__ out) {
  int row = blockIdx.x * 4 + (threadIdx.x >> 6);    // 8192 rows, 4 rows/block
  int lane = threadIdx.x & 63;
  const float* xr = x + (size_t)row * D_ + lane * 8;
  f32x4 v0 = *(const f32x4*)xr;
  f32x4 v1 = *(const f32x4*)(xr + 4);
  float s = 0.f, sq = 0.f;
  #pragma unroll
  for (int j = 0; j < 4; j++) { s += v0[j] + v1[j]; sq += v0[j] * v0[j] + v1[j] * v1[j]; }
  #pragma unroll
  for (int m = 1; m < 64; m <<= 1) { s += __shfl_xor(s, m); sq += __shfl_xor(sq, m); }
  float mean = s * (1.f / D_);
  float var = sq * (1.f / D_) - mean * mean;
  float rstd = rsqrtf(var + 1e-5f);
  f32x4 g0 = *(const f32x4*)(g + lane * 8);
  f32x4 g1 = *(const f32x4*)(g + lane * 8 + 4);
  f32x4 b0 = *(const f32x4*)(bta + lane * 8);
  f32x4 b1 = *(const f32x4*)(bta + lane * 8 + 4);
  u16x8 o;
  #pragma unroll
  for (int j = 0; j < 4; j++) {
    o[j]     = f2b((v0[j] - mean) * rstd * g0[j] + b0[j]);
    o[4 + j] = f2b((v1[j] - mean) * rstd * g1[j] + b1[j]);
  }
  *(u16x8*)(out + (size_t)row * D_ + lane * 8) = o;
}

// ============ GEMM tiles: 128x128, BK=32, double-buffered, XCD-remapped 1-D grid ============
// staging swizzle: stored[row][p] = global chunk p ^ s(row), s(row)=(row>>1)&3

// ---------------- QKV GEMM with fused type-emb + RoPE + scale + head-layout epilogue ----------------
__global__ __launch_bounds__(256) void gemm_qkv(const u16* __restrict__ A,
    const u16* __restrict__ Bt,
    const int* __restrict__ x_type, const float* __restrict__ type_emb,
    const float* __restrict__ rqc, const float* __restrict__ rqs,
    const float* __restrict__ rkc, const float* __restrict__ rks,
    u16* __restrict__ qT, u16* __restrict__ kT, u16* __restrict__ vT) {
  __shared__ u16 lA[2][4096];
  __shared__ u16 lB[2][4096];
  const int K = 512;
  const int tid = threadIdx.x, lane = tid & 63, w = tid >> 6;
  const int wm = w >> 1, wn = w & 1;
  // XCD remap: 768 blocks -> each XCD gets 8 contiguous row-panels (A reuse in its L2)
  int swz = (blockIdx.x & 7) * 96 + (blockIdx.x >> 3);
  int byy = swz / 12, bxx = swz - byy * 12;
  const size_t bm = (size_t)byy * 128;
  const size_t bn = (size_t)bxx * 128;

  const int r0 = tid >> 2;
  const int cs = ((tid & 3) ^ ((r0 >> 1) & 3)) * 8;
  const u16* a0 = A + (bm + r0) * K + cs;
  const u16* a1 = A + (bm + 64 + r0) * K + cs;
  const u16* b0 = Bt + (bn + r0) * K + cs;
  const u16* b1p = Bt + (bn + 64 + r0) * K + cs;

  int aoff[4], boff[4];
  #pragma unroll
  for (int i = 0; i < 4; i++) {
    int ra = wm * 64 + i * 16 + (lane & 15);
    aoff[i] = ra * 64 + (((lane >> 4) ^ ((ra >> 1) & 3)) * 16);
    int rb = wn * 64 + i * 16 + (lane & 15);
    boff[i] = rb * 64 + (((lane >> 4) ^ ((rb >> 1) & 3)) * 16);
  }

  auto stage = [&](int k0, int buf) {
    char* ad = (char*)lA + buf * 8192 + w * 1024;
    char* bd = (char*)lB + buf * 8192 + w * 1024;
    gld16(a0 + k0, ad);
    gld16(a1 + k0, ad + 4096);
    gld16(b0 + k0, bd);
    gld16(b1p + k0, bd + 4096);
  };

  f32x4 acc[4][4] = {};
  stage(0, 0);
  __syncthreads();
  int cur = 0;
  for (int k0 = 0; k0 < K; k0 += 32) {
    if (k0 + 32 < K) stage(k0 + 32, cur ^ 1);     // prefetch overlaps compute below
    const char* lAc = (const char*)lA + cur * 8192;
    const char* lBc = (const char*)lB + cur * 8192;
    bf16x8 af[4], bf[4];
    #pragma unroll
    for (int i = 0; i < 4; i++) af[i] = *(const bf16x8*)(lAc + aoff[i]);
    #pragma unroll
    for (int n = 0; n < 4; n++) bf[n] = *(const bf16x8*)(lBc + boff[n]);
    __builtin_amdgcn_s_setprio(1);
    #pragma unroll
    for (int i = 0; i < 4; i++)
      #pragma unroll
      for (int n = 0; n < 4; n++)
        acc[i][n] = mfma16(af[i], bf[n], acc[i][n]);
    __builtin_amdgcn_s_setprio(0);
    __syncthreads();
    cur ^= 1;
  }

  // fused epilogue. block-uniform region: 0=q (cols 0..511), 1=k, 2=v
  const int region = (int)(bn >> 9);
  #pragma unroll
  for (int i = 0; i < 4; i++) {
    #pragma unroll
    for (int jj = 0; jj < 4; jj++) {
      int row = (int)bm + wm * 64 + i * 16 + (lane >> 4) * 4 + jj;   // bt index
      int b = row >> 10, t = row & 1023;
      if (region == 0) {
        int ty = x_type[b * TP1 + t];
        #pragma unroll
        for (int n = 0; n < 4; n++) {
          int cloc = (int)bn + wn * 64 + n * 16 + (lane & 15);       // 0..511
          int h = cloc >> 6, hd = cloc & 63;
          float v = acc[i][n][jj] + type_emb[(size_t)ty * 1024 + cloc];
          float vp = __shfl_xor(v, 1);
          if (hd < 32) {
            int p = hd >> 1;
            float c = rqc[row * 16 + p], s = rqs[row * 16 + p];
            v = (hd & 1) ? (v * c + vp * s) : (v * c - vp * s);
          }
          qT[((size_t)(b * 8 + h) * T_ + t) * 64 + hd] = f2b(v * QSCALE);
        }
      } else if (region == 1) {
        int ty = x_type[b * TP1 + t + 1];
        #pragma unroll
        for (int n = 0; n < 4; n++) {
          int cloc = (int)bn - 512 + wn * 64 + n * 16 + (lane & 15); // 0..511
          int h = cloc >> 6, hd = cloc & 63;
          float v = acc[i][n][jj] + type_emb[(size_t)ty * 1024 + 512 + cloc];
          float vp = __shfl_xor(v, 1);
          if (hd < 32) {
            int p = hd >> 1;
            float c = rkc[row * 16 + p], s = rks[row * 16 + p];
            v = (hd & 1) ? (v * c + vp * s) : (v * c - vp * s);
          }
          kT[((size_t)(b * 8 + h) * T_ + t) * 64 + hd] = f2b(v);
        }
      } else {
        #pragma unroll
        for (int n = 0; n < 4; n++) {
          int cloc = (int)bn - 1024 + wn * 64 + n * 16 + (lane & 15);
          int h = cloc >> 6, hd = cloc & 63;
          vT[((size_t)(b * 8 + h) * 64 + hd) * T_ + t] = f2b(acc[i][n][jj]);
        }
      }
    }
  }
}

// ---------------- FF1 GEMM on interleaved W1i: standard 2-operand + in-lane SwiGLU ----------------
__global__ __launch_bounds__(256) void gemm_ff1(const u16* __restrict__ A,
    const u16* __restrict__ Bt, const float* __restrict__ b1,
    u16* __restrict__ outp) {
  __shared__ u16 lA[2][4096];
  __shared__ u16 lB[2][4096];
  const int K = 512;
  const int tid = threadIdx.x, lane = tid & 63, w = tid >> 6;
  const int wm = w >> 1, wn = w & 1;
  int swz = (blockIdx.x & 7) * 128 + (blockIdx.x >> 3);   // 1024 blocks
  int byy = swz >> 4, bxx = swz & 15;                     // per XCD: 8 row-panels x all cols
  const size_t bm = (size_t)byy * 128;
  const size_t bn = (size_t)bxx * 128;

  const int r0 = tid >> 2;
  const int cs = ((tid & 3) ^ ((r0 >> 1) & 3)) * 8;
  const u16* a0 = A + (bm + r0) * K + cs;
  const u16* a1 = A + (bm + 64 + r0) * K + cs;
  const u16* b0 = Bt + (bn + r0) * K + cs;
  const u16* b1p = Bt + (bn + 64 + r0) * K + cs;

  int aoff[4], boff[4];
  #pragma unroll
  for (int i = 0; i < 4; i++) {
    int ra = wm * 64 + i * 16 + (lane & 15);
    aoff[i] = ra * 64 + (((lane >> 4) ^ ((ra >> 1) & 3)) * 16);
    int rb = wn * 64 + i * 16 + (lane & 15);
    boff[i] = rb * 64 + (((lane >> 4) ^ ((rb >> 1) & 3)) * 16);
  }

  auto stage = [&](int k0, int buf) {
    char* ad = (char*)lA + buf * 8192 + w * 1024;
    char* bd = (char*)lB + buf * 8192 + w * 1024;
    gld16(a0 + k0, ad);
    gld16(a1 + k0, ad + 4096);
    gld16(b0 + k0, bd);
    gld16(b1p + k0, bd + 4096);
  };

  f32x4 acc[4][4] = {};
  stage(0, 0);
  __syncthreads();
  int cur = 0;
  for (int k0 = 0; k0 < K; k0 += 32) {
    if (k0 + 32 < K) stage(k0 + 32, cur ^ 1);
    const char* lAc = (const char*)lA + cur * 8192;
    const char* lBc = (const char*)lB + cur * 8192;
    bf16x8 af[4], bf[4];
    #pragma unroll
    for (int i = 0; i < 4; i++) af[i] = *(const bf16x8*)(lAc + aoff[i]);
    #pragma unroll
    for (int n = 0; n < 4; n++) bf[n] = *(const bf16x8*)(lBc + boff[n]);
    __builtin_amdgcn_s_setprio(1);
    #pragma unroll
    for (int i = 0; i < 4; i++)
      #pragma unroll
      for (int n = 0; n < 4; n++)
        acc[i][n] = mfma16(af[i], bf[n], acc[i][n]);
    __builtin_amdgcn_s_setprio(0);
    __syncthreads();
    cur ^= 1;
  }
  // epilogue: real col c = bn/2 + wn*32 + np*16 + (lane&15); a = acc[i][2np], g = acc[i][2np+1]
  #pragma unroll
  for (int np = 0; np < 2; np++) {
    int c = ((int)bn >> 1) + wn * 32 + np * 16 + (lane & 15);
    float bav = b1[c], bgv = b1[1024 + c];
    #pragma unroll
    for (int i = 0; i < 4; i++) {
      #pragma unroll
      for (int jj = 0; jj < 4; jj++) {
        int row = (int)bm + wm * 64 + i * 16 + (lane >> 4) * 4 + jj;
        float av = acc[i][2 * np][jj] + bav;
        float gv = acc[i][2 * np + 1][jj] + bgv;
        float sg = gv / (1.f + expf(-gv));
        outp[(size_t)row * 1024 + c] = f2b(sg * av);
      }
    }
  }
}

// ---------------- FF2 GEMM, 512 thr / 8 waves ----------------
__global__ __launch_bounds__(512) void gemm_ff2(const u16* __restrict__ A,
    const u16* __restrict__ Bt, const float* __restrict__ bias,
    float* __restrict__ C) {
  __shared__ u16 lA[2][4096];
  __shared__ u16 lB[2][4096];
  const int K = 1024, N = 512;
  const int tid = threadIdx.x, lane = tid & 63, w = tid >> 6;   // w 0..7
  const int wm = w >> 2, wn = w & 3;                            // 2x4 waves: 64x32 each
  int swz = (blockIdx.x & 7) * 32 + (blockIdx.x >> 3);          // 256 blocks
  int byy = swz >> 2, bxx = swz & 3;
  const size_t bm = (size_t)byy * 128;
  const size_t bn = (size_t)bxx * 128;

  const int r0 = tid >> 2;                                      // 0..127
  const int cs = ((tid & 3) ^ ((r0 >> 1) & 3)) * 8;
  const u16* a0 = A + (bm + r0) * K + cs;
  const u16* b0 = Bt + (bn + r0) * K + cs;

  int aoff[4], boff[2];
  #pragma unroll
  for (int i = 0; i < 4; i++) {
    int ra = wm * 64 + i * 16 + (lane & 15);
    aoff[i] = ra * 64 + (((lane >> 4) ^ ((ra >> 1) & 3)) * 16);
  }
  #pragma unroll
  for (int n = 0; n < 2; n++) {
    int rb = wn * 32 + n * 16 + (lane & 15);
    boff[n] = rb * 64 + (((lane >> 4) ^ ((rb >> 1) & 3)) * 16);
  }

  auto stage = [&](int k0, int buf) {      // 512 thr: one call covers full 8KB tile
    gld16(a0 + k0, (char*)lA + buf * 8192 + w * 1024);
    gld16(b0 + k0, (char*)lB + buf * 8192 + w * 1024);
  };

  f32x4 acc[4][2] = {};
  stage(0, 0);
  __syncthreads();
  int cur = 0;
  for (int k0 = 0; k0 < K; k0 += 32) {
    if (k0 + 32 < K) stage(k0 + 32, cur ^ 1);
    const char* lAc = (const char*)lA + cur * 8192;
    const char* lBc = (const char*)lB + cur * 8192;
    bf16x8 af[4], bf[2];
    #pragma unroll
    for (int i = 0; i < 4; i++) af[i] = *(const bf16x8*)(lAc + aoff[i]);
    #pragma unroll
    for (int n = 0; n < 2; n++) bf[n] = *(const bf16x8*)(lBc + boff[n]);
    __builtin_amdgcn_s_setprio(1);
    #pragma unroll
    for (int i = 0; i < 4; i++)
      #pragma unroll
      for (int n = 0; n < 2; n++)
        acc[i][n] = mfma16(af[i], bf[n], acc[i][n]);
    __builtin_amdgcn_s_setprio(0);
    __syncthreads();
    cur ^= 1;
  }
  #pragma unroll
  for (int i = 0; i < 4; i++) {
    size_t mrow = bm + wm * 64 + i * 16 + (lane >> 4) * 4;
    #pragma unroll
    for (int n = 0; n < 2; n++) {
      size_t col = bn + wn * 32 + n * 16 + (lane & 15);
      float bv = bias[col];
      #pragma unroll
      for (int jj = 0; jj < 4; jj++) {
        size_t idx = (mrow + jj) * (size_t)N + col;
        C[idx] = acc[i][n][jj] + bv + C[idx];   // in-place residual
      }
    }
  }
}

// ---------------- causal flash attention + residual: out = x_value + attn ----------------
// 128 q-rows per block (8 waves / 512 thr): each K/V tile staged once serves 2x q-rows
// vs the 64-row version -> 4608 total tile-iters (was 8704). Swapped-operand QK^T,
// in-register softmax, cvt_pk P-pack (zero shuffles), defer-max, LPT + XCD chunking.
__global__ __launch_bounds__(512) void attn_kernel(const u16* __restrict__ qT,
    const u16* __restrict__ kT, const u16* __restrict__ vT,
    const float* __restrict__ xv, float* __restrict__ X) {
  int s0 = (blockIdx.x & 7) * 64 + (blockIdx.x >> 3);   // 512 blocks, 8 bh per XCD
  const int bh = s0 >> 3;
  const int qp = 7 - (s0 & 7);             // LPT: longest (qp=7) first per bh
  const int b = bh >> 3, h = bh & 7;
  const int tid = threadIdx.x, lane = tid & 63, w = tid >> 6;   // w 0..7
  const int q = lane & 15, g = lane >> 4;
  __shared__ u16 lK[2][4096];
  __shared__ u16 lV[2][4096];

  const int qrow0 = qp * 128 + w * 16;     // this wave's q-strip start
  bf16x8 qf[2];
  {
    const u16* qp_ = qT + ((size_t)bh * T_ + qrow0 + q) * 64 + g * 8;
    qf[0] = *(const bf16x8*)qp_;
    qf[1] = *(const bf16x8*)(qp_ + 32);
  }
  f32x4 acc[4] = {};
  float mr = -1e30f, lr = 0.f;

  const int sr = tid >> 3;                 // 0..63: 512 thr cover the full 64-row tile
  const int scs = ((tid & 7) ^ (sr & 7)) * 8;
  const u16* kb = kT + ((size_t)bh * T_ + sr) * 64 + scs;
  const u16* vb = vT + ((size_t)bh * 64 + sr) * T_ + scs;

  auto stage = [&](int j, int buf) {
    gld16(kb + (size_t)j * 4096, (char*)lK + buf * 8192 + w * 1024);
    gld16(vb + j * 64, (char*)lV + buf * 8192 + w * 1024);
  };

  const int jmax = 2 * qp + 2;
  stage(0, 0);
  __syncthreads();
  int cur = 0;
  for (int j = 0; j < jmax; j++) {
    if (j + 1 < jmax) stage(j + 1, cur ^ 1);   // prefetch next tile under compute
    const char* lKc = (const char*)lK + cur * 8192;
    const char* lVc = (const char*)lV + cur * 8192;

    if (j * 64 <= qrow0 + 15) {            // wave participates in this k-tile
      // QK^T swapped: s[n][i] = S[k = j*64 + n*16+g*4+i][qrow0+q]
      f32x4 s[4] = {};
      __builtin_amdgcn_s_setprio(1);
      #pragma unroll
      for (int ka = 0; ka < 2; ka++) {
        #pragma unroll
        for (int n = 0; n < 4; n++) {
          bf16x8 kf = *(const bf16x8*)(lKc + (n * 16 + q) * 128 +
                                       (((ka * 4 + g) ^ (q & 7)) * 16));
          s[n] = mfma16(kf, qf[ka], s[n]);
        }
      }
      __builtin_amdgcn_s_setprio(0);
      if (j * 64 + 63 > qrow0) {           // diagonal-region mask
        int qrow = qrow0 + q;
        #pragma unroll
        for (int n = 0; n < 4; n++)
          #pragma unroll
          for (int i = 0; i < 4; i++)
            if (j * 64 + n * 16 + g * 4 + i > qrow) s[n][i] = -1e30f;
      }
      // in-register softmax: one q-row per lane
      float mt = fmaxf(fmaxf(fmaxf(s[0][0], s[0][1]), fmaxf(s[0][2], s[0][3])),
                       fmaxf(fmaxf(s[1][0], s[1][1]), fmaxf(s[1][2], s[1][3])));
      mt = fmaxf(mt, fmaxf(fmaxf(fmaxf(s[2][0], s[2][1]), fmaxf(s[2][2], s[2][3])),
                           fmaxf(fmaxf(s[3][0], s[3][1]), fmaxf(s[3][2], s[3][3]))));
      mt = fmaxf(mt, __shfl_xor(mt, 16));
      mt = fmaxf(mt, __shfl_xor(mt, 32));
      if (__any(mt > mr + 8.f)) {          // defer-max: skip rescale when growth < 2^8
        float mnew = fmaxf(mr, mt);
        float sc = exp2f(mr - mnew);
        mr = mnew;
        lr *= sc;
        #pragma unroll
        for (int t = 0; t < 4; t++) acc[t] *= sc;
      }
      float p[4][4];
      float ps = 0.f;
      #pragma unroll
      for (int n = 0; n < 4; n++)
        #pragma unroll
        for (int i = 0; i < 4; i++) { p[n][i] = exp2f(s[n][i] - mr); ps += p[n][i]; }
      ps += __shfl_xor(ps, 16);
      ps += __shfl_xor(ps, 32);
      lr += ps;
      // pack P into PV B-frags (lane-local, no shuffles)
      U8 pa[2];
      #pragma unroll
      for (int kt = 0; kt < 2; kt++) {
        pa[kt].u[0] = cvtpk(p[2 * kt][0], p[2 * kt][1]);
        pa[kt].u[1] = cvtpk(p[2 * kt][2], p[2 * kt][3]);
        pa[kt].u[2] = cvtpk(p[2 * kt + 1][0], p[2 * kt + 1][1]);
        pa[kt].u[3] = cvtpk(p[2 * kt + 1][2], p[2 * kt + 1][3]);
      }
      // PV: O^T[d][q] += V^T[d][k'] * P^T[k'][q], k'(g,e) = kt*32+(e>>2)*16+g*4+(e&3)
      __builtin_amdgcn_s_setprio(1);
      #pragma unroll
      for (int t = 0; t < 4; t++) {
        const char* vr = lVc + (t * 16 + q) * 128 + (g & 1) * 8;
        #pragma unroll
        for (int kt = 0; kt < 2; kt++) {
          u32x2 lo = *(const u32x2*)(vr + (((kt * 4 + (g >> 1)) ^ (q & 7)) * 16));
          u32x2 hi = *(const u32x2*)(vr + (((kt * 4 + 2 + (g >> 1)) ^ (q & 7)) * 16));
          U8 af;
          af.u[0] = lo[0]; af.u[1] = lo[1]; af.u[2] = hi[0]; af.u[3] = hi[1];
          acc[t] = mfma16(af.v, pa[kt].v, acc[t]);
        }
      }
      __builtin_amdgcn_s_setprio(0);
    }
    __syncthreads();                       // drains prefetch; publishes buf cur^1
    cur ^= 1;
  }
  // epilogue: lane owns q-row (qrow0+q), cols d = t*16+g*4+{0..3} -> f32x4
  {
    float inv = 1.f / lr;
    size_t base = ((size_t)b * T_ + qrow0 + q) * D_ + h * 64 + g * 4;
    #pragma unroll
    for (int t = 0; t < 4; t++) {
      f32x4 r = *(const f32x4*)(xv + base + t * 16);
      f32x4 o;
      #pragma unroll
      for (int i = 0; i < 4; i++) o[i] = r[i] + acc[t][i] * inv;
      *(f32x4*)(X + base + t * 16) = o;
    }
  }
}

// ------------------------------- launch -------------------------------
extern "C" void kernel_launch(void* const* d_in, const int* in_sizes, int n_in,
                              void* d_out, int out_size, void* d_ws, size_t ws_size,
                              hipStream_t stream) {
  const int*   x_type   = (const int*)d_in[0];
  const float* x_value  = (const float*)d_in[1];
  const float* seq      = (const float*)d_in[2];
  const float* W_attn   = (const float*)d_in[3];
  const float* type_emb = (const float*)d_in[4];
  const float* ln1_g    = (const float*)d_in[5];
  const float* ln1_b    = (const float*)d_in[6];
  const float* ln2_g    = (const float*)d_in[7];
  const float* ln2_b    = (const float*)d_in[8];
  const float* W1       = (const float*)d_in[9];
  const float* b1       = (const float*)d_in[10];
  const float* W2       = (const float*)d_in[11];
  const float* b2       = (const float*)d_in[12];
  float* out = (float*)d_out;
  char* ws = (char*)d_ws;

  // workspace layout — total ~38.5 MiB
  u16*   WtA  = (u16*)(ws + 0);             // 1536x512 bf16  1.5 MiB
  u16*   W1i  = (u16*)(ws + 1572864);       // 2048x512 bf16 interleaved a/gate  2 MiB
  u16*   W2t  = (u16*)(ws + 3670016);       // 512x1024 bf16  1 MiB
  float* rqc  = (float*)(ws + 4718592);     // 4 rope tables, 512 KiB each
  float* rqs  = (float*)(ws + 5242880);
  float* rkc  = (float*)(ws + 5767168);
  float* rks  = (float*)(ws + 6291456);
  u16*   hbuf = (u16*)(ws + 6815744);       // 8192x512 bf16 (h, then h2)  8 MiB
  u16*   qTb  = (u16*)(ws + 15204352);      // (B,H,T,64) bf16  8 MiB
  u16*   kTb  = (u16*)(ws + 23592960);      // 8 MiB
  u16*   vTb  = (u16*)(ws + 31981568);      // (B,H,64,T) bf16  8 MiB
  u16*   ff1a = (u16*)(ws + 15204352);      // 8192x1024 bf16 16 MiB, aliases qT+kT (dead post-attn)

  prep_kernel<<<1088, 256, 0, stream>>>(W_attn, W1, W2, seq, WtA, W1i, W2t,
                                        rqc, rqs, rkc, rks);
  ln_kernel<<<B_ * T_ / 4, 256, 0, stream>>>(x_value, ln1_g, ln1_b, hbuf);
  gemm_qkv<<<768, 256, 0, stream>>>(hbuf, WtA, x_type, type_emb,
                                    rqc, rqs, rkc, rks, qTb, kTb, vTb);
  attn_kernel<<<512, 512, 0, stream>>>(qTb, kTb, vTb, x_value, out);
  ln_kernel<<<B_ * T_ / 4, 256, 0, stream>>>(out, ln2_g, ln2_b, hbuf);
  gemm_ff1<<<1024, 256, 0, stream>>>(hbuf, W1i, b1, ff1a);
  gemm_ff2<<<256, 512, 0, stream>>>(ff1a, W2t, b2, out);
}